// Round 4
// baseline (772.024 us; speedup 1.0000x reference)
//
#include <hip/hip_runtime.h>
#include <math.h>

// DualRec 2-layer transformer-XL model, MI355X — round 13.
// r13 (from r12 counters: FF1 still top @65.8µs, MfmaUtil 21 / VALUBusy 36 /
// HBM 19% — all pipes idle; 128² 2-barrier structure is latency-bound):
//   NEW mfma_gemm256: 8-phase 256² schedule (T2+T3+T4+T5) for QKV + FF1.
//   512 thr / 8 waves (2x4), BK=64, 128KB dbuf LDS, per-wave 128x64 C.
//   Per K-tile: 4 quadrant-phases {ds_reads | stage 1 half-tile -> barrier ->
//   setprio+16 MFMA -> barrier}; lead-5 half-tile staging, boundary
//   vmcnt(2) (never 0 mid-loop). Chunk-XOR swizzle ch^=(row&7) via
//   pre-swizzled global source (rule #21), conflict-free (r12 measured 0).
// Wo/FF2/k_r (N=512: only 128 blocks at 256² -> CU-starved) keep r12 kernel.
// Carried: r12 triple-buffer counted-vmcnt 128² GEMM, r11 bn-fastest XCD
// swizzle + A&S erf GELU, r10 attn LDS XOR swizzle + __expf softmax.

#define S_  512
#define B_  32
#define D_  512
#define NH  8
#define DH  64
#define DI  2048
#define M_  (S_*B_)
#define QKV_LD 1536
#define WL  3407872   // per-layer wbuf elements (6.5 MiB)
#define FP32_ONE 0x3F800000u

typedef unsigned short ushort_t;
typedef __attribute__((ext_vector_type(8))) short short8;
typedef __attribute__((ext_vector_type(4))) float f32x4;

__constant__ int OMEGA_C[8] = {2, 3, 4, 5, 7, 11, 21, 50};

__device__ __forceinline__ float b2f(ushort_t us) {
    return __uint_as_float(((unsigned int)us) << 16);
}
__device__ __forceinline__ ushort_t f2b(float f) {
    unsigned int u = __float_as_uint(f);
    return (ushort_t)((u + 0x7fffu + ((u >> 16) & 1u)) >> 16);
}
__device__ __forceinline__ float ldx(const void* p, size_t idx, bool isbf) {
    return isbf ? b2f(((const ushort_t*)p)[idx]) : ((const float*)p)[idx];
}
__device__ __forceinline__ void async16(const ushort_t* g, ushort_t* l) {
    __builtin_amdgcn_global_load_lds(
        (const __attribute__((address_space(1))) unsigned int*)g,
        (__attribute__((address_space(3))) unsigned int*)l, 16, 0, 0);
}

// Branch-free exact-GELU: 0.5*v*(1+erf(v/sqrt2)) via A&S 7.1.26 (|err|<=1.5e-7).
__device__ __forceinline__ float fast_gelu(float v) {
    float x  = v * 0.7071067811865475f;
    float ax = fabsf(x);
    float t  = __builtin_amdgcn_rcpf(fmaf(0.3275911f, ax, 1.f));
    float p  = fmaf(fmaf(fmaf(fmaf(1.061405429f, t, -1.453152027f),
                              t, 1.421413741f),
                         t, -0.284496736f),
                    t, 0.254829592f) * t;
    float e    = __expf(-ax * ax);
    float erfa = fmaf(-p, e, 1.f);          // erf(|x|)
    float erfx = copysignf(erfa, x);
    return 0.5f * v * (1.f + erfx);
}

// ---- DPP reductions ----
#define DPPA(v, ctrl) v += __int_as_float(__builtin_amdgcn_update_dpp(0, __float_as_int(v), ctrl, 0xf, 0xf, true))
__device__ __forceinline__ void dpp_sum64(float& v) {
    DPPA(v, 0x111); DPPA(v, 0x112); DPPA(v, 0x114);
    DPPA(v, 0x118); DPPA(v, 0x142); DPPA(v, 0x143);
}
#define DPPROR(v, ctrl) __int_as_float(__builtin_amdgcn_update_dpp(__float_as_int(v), __float_as_int(v), ctrl, 0xf, 0xf, false))
__device__ __forceinline__ float row16_sum(float v) {
    v += DPPROR(v, 0x128); v += DPPROR(v, 0x124);
    v += DPPROR(v, 0x122); v += DPPROR(v, 0x121);
    return v;
}
__device__ __forceinline__ float row16_max(float v) {
    v = fmaxf(v, DPPROR(v, 0x128)); v = fmaxf(v, DPPROR(v, 0x124));
    v = fmaxf(v, DPPROR(v, 0x122)); v = fmaxf(v, DPPROR(v, 0x121));
    return v;
}
__device__ __forceinline__ float rlane(float v, int l) {
    return __int_as_float(__builtin_amdgcn_readlane(__float_as_int(v), l));
}

__global__ __launch_bounds__(256) void embed_kernel(const int* __restrict__ ids,
                                                    const void* __restrict__ emb,
                                                    ushort_t* __restrict__ h,
                                                    const unsigned int* __restrict__ dtp) {
    const bool isbf = (dtp[0] != FP32_ONE);
    int idx = blockIdx.x * 256 + threadIdx.x;        // over M_*D_/8
    int d8 = idx & 63;
    int row = idx >> 6;                              // i*B + b
    int s = row >> 5, b = row & 31;
    int id = ids[b * S_ + s];
    size_t src = (size_t)id * D_ + d8 * 8;
    if (isbf) {
        *(uint4*)(h + (size_t)row * D_ + d8 * 8) = *(const uint4*)((const ushort_t*)emb + src);
    } else {
        const float* e = (const float*)emb + src;
        float4 a0 = ((const float4*)e)[0], a1 = ((const float4*)e)[1];
        uint4 pk;
        pk.x = (unsigned)f2b(a0.x) | ((unsigned)f2b(a0.y) << 16);
        pk.y = (unsigned)f2b(a0.z) | ((unsigned)f2b(a0.w) << 16);
        pk.z = (unsigned)f2b(a1.x) | ((unsigned)f2b(a1.y) << 16);
        pk.w = (unsigned)f2b(a1.z) | ((unsigned)f2b(a1.w) << 16);
        *(uint4*)(h + (size_t)row * D_ + d8 * 8) = pk;
    }
}

__global__ __launch_bounds__(256) void posemb_kernel(ushort_t* __restrict__ pos) {
    int flat = blockIdx.x * 256 + threadIdx.x;       // over 1024*256
    int p = flat >> 8, k = flat & 255;
    float inv = expf((float)k * -0.035977892078031f);
    float val = (512.0f - (float)p) * inv;
    pos[p * D_ + k]       = f2b(sinf(val));
    pos[p * D_ + 256 + k] = f2b(cosf(val));
}

__global__ __launch_bounds__(256) void transp_cvt4(
    const void* __restrict__ s0, const void* __restrict__ s1,
    const void* __restrict__ s2, const void* __restrict__ s3,
    ushort_t* __restrict__ wbuf, const unsigned int* __restrict__ dtp) {
    const bool isbf = (dtp[0] != FP32_ONE);
    __shared__ float tt[32][33];
    int z = blockIdx.z, layer = z >> 2, t4 = z & 3;
    const void* srcs[4] = {s0, s1, s2, s3};
    const void* in = srcs[t4];
    size_t inoff = (size_t)layer * 262144;
    ushort_t* out = wbuf + (size_t)layer * WL + (size_t)t4 * 262144;
    int tx = threadIdx.x & 31, ty = threadIdx.x >> 5;
    int n0 = blockIdx.x * 32, k0 = blockIdx.y * 32;
#pragma unroll
    for (int it = 0; it < 4; ++it)
        tt[ty + it * 8][tx] = ldx(in, inoff + (size_t)(k0 + ty + it * 8) * 512 + n0 + tx, isbf);
    __syncthreads();
#pragma unroll
    for (int it = 0; it < 4; ++it)
        out[(size_t)(n0 + ty + it * 8) * 512 + k0 + tx] = f2b(tt[tx][ty + it * 8]);
}

__global__ __launch_bounds__(256) void transp_cvtL(const void* __restrict__ in, size_t perlin,
                                                   ushort_t* __restrict__ wbuf, size_t outoff,
                                                   const unsigned int* __restrict__ dtp,
                                                   int K, int N) {
    const bool isbf = (dtp[0] != FP32_ONE);
    __shared__ float tt[32][33];
    int layer = blockIdx.z;
    size_t inoff = (size_t)layer * perlin;
    ushort_t* out = wbuf + (size_t)layer * WL + outoff;
    int tx = threadIdx.x & 31, ty = threadIdx.x >> 5;
    int n0 = blockIdx.x * 32, k0 = blockIdx.y * 32;
#pragma unroll
    for (int it = 0; it < 4; ++it)
        tt[ty + it * 8][tx] = ldx(in, inoff + (size_t)(k0 + ty + it * 8) * N + n0 + tx, isbf);
    __syncthreads();
#pragma unroll
    for (int it = 0; it < 4; ++it)
        out[(size_t)(n0 + ty + it * 8) * K + k0 + tx] = f2b(tt[tx][ty + it * 8]);
}

__global__ __launch_bounds__(256) void cvtL(const void* __restrict__ in, size_t perlin,
                                            ushort_t* __restrict__ wbuf, size_t outoff,
                                            const unsigned int* __restrict__ dtp, int nelem) {
    const bool isbf = (dtp[0] != FP32_ONE);
    int layer = blockIdx.z;
    int i = blockIdx.x * 256 + threadIdx.x;
    if (i < nelem)
        wbuf[(size_t)layer * WL + outoff + i] = f2b(ldx(in, (size_t)layer * perlin + i, isbf));
}

// ---------------- r12 128x128 GEMM (kept for N=512 shapes) ----------------
template<int EPI>
__global__ __launch_bounds__(256)
void mfma_gemm(const ushort_t* __restrict__ A, int lda,
               const ushort_t* __restrict__ Bt, int ldb,
               const void* __restrict__ biasv, size_t biasoff,
               ushort_t* __restrict__ C, int ldc,
               const unsigned int* __restrict__ dtp, int M, int N, int K) {
    const bool isbf = (dtp[0] != FP32_ONE);
    __shared__ ushort_t As[3][128 * 32];
    __shared__ ushort_t Bs[3][128 * 32];
    const int tid = threadIdx.x;
    const int nwg = gridDim.x * gridDim.y;
    const int wg  = blockIdx.y * gridDim.x + blockIdx.x;
    const int cpx = nwg >> 3;
    const int swz = (wg & 7) * cpx + (wg >> 3);
    const int bm = (swz / gridDim.y) * 128;
    const int bn = (swz % gridDim.y) * 128;
    const int w = tid >> 6, lane = tid & 63;
    const int wr = w >> 1, wc = w & 1;
    const int quad = lane >> 4, l16 = lane & 15;
    const int rsub = lane >> 2;
    const int kcg  = (lane & 3) ^ ((rsub >> 1) & 3);
    const int fsw  = (l16 >> 1) & 3;

    const ushort_t* ga0 = A  + (size_t)(bm + w * 16 + rsub) * lda + kcg * 8;
    const ushort_t* ga1 = A  + (size_t)(bm + (4 + w) * 16 + rsub) * lda + kcg * 8;
    const ushort_t* gb0 = Bt + (size_t)(bn + w * 16 + rsub) * ldb + kcg * 8;
    const ushort_t* gb1 = Bt + (size_t)(bn + (4 + w) * 16 + rsub) * ldb + kcg * 8;

#define STAGE_T(kt, bi) do {                                  \
        int _k0 = (kt) << 5;                                  \
        async16(ga0 + _k0, As[bi] + w * 512);                 \
        async16(gb0 + _k0, Bs[bi] + w * 512);                 \
        async16(ga1 + _k0, As[bi] + (4 + w) * 512);           \
        async16(gb1 + _k0, Bs[bi] + (4 + w) * 512);           \
    } while (0)

    f32x4 acc[4][4];
#pragma unroll
    for (int i = 0; i < 4; ++i)
#pragma unroll
        for (int j = 0; j < 4; ++j)
#pragma unroll
            for (int r = 0; r < 4; ++r) acc[i][j][r] = 0.f;

    const int nt = K >> 5;
    STAGE_T(0, 0);
    STAGE_T(1, 1);
    int cur = 0, nxt = 2;
    for (int t = 0; t < nt; ++t) {
        if (t + 2 < nt) {
            STAGE_T(t + 2, nxt);
            asm volatile("s_waitcnt vmcnt(8)" ::: "memory");
        } else if (t + 1 < nt) {
            asm volatile("s_waitcnt vmcnt(4)" ::: "memory");
        } else {
            asm volatile("s_waitcnt vmcnt(0)" ::: "memory");
        }
        __builtin_amdgcn_s_barrier();
        asm volatile("" ::: "memory");

        short8 af[4], bf[4];
#pragma unroll
        for (int tt = 0; tt < 4; ++tt) {
            int ra = wr * 64 + tt * 16 + l16;
            int rb = wc * 64 + tt * 16 + l16;
            af[tt] = *(const short8*)(As[cur] + ra * 32 + ((quad ^ fsw) * 8));
            bf[tt] = *(const short8*)(Bs[cur] + rb * 32 + ((quad ^ fsw) * 8));
        }
#pragma unroll
        for (int tr = 0; tr < 4; ++tr)
#pragma unroll
            for (int tc = 0; tc < 4; ++tc)
                acc[tr][tc] = __builtin_amdgcn_mfma_f32_16x16x32_bf16(bf[tc], af[tr], acc[tr][tc], 0, 0, 0);

        asm volatile("s_waitcnt lgkmcnt(0)" ::: "memory");
        __builtin_amdgcn_s_barrier();
        cur = cur == 2 ? 0 : cur + 1;
        nxt = nxt == 2 ? 0 : nxt + 1;
    }
#undef STAGE_T

    float bv[4][4];
    if (EPI >= 1) {
#pragma unroll
        for (int tc = 0; tc < 4; ++tc)
#pragma unroll
            for (int r = 0; r < 4; ++r)
                bv[tc][r] = ldx(biasv, biasoff + bn + wc * 64 + tc * 16 + quad * 4 + r, isbf);
    }
#pragma unroll
    for (int tr = 0; tr < 4; ++tr) {
        int grow = bm + wr * 64 + tr * 16 + l16;
#pragma unroll
        for (int tc = 0; tc < 4; ++tc) {
            int gcb = bn + wc * 64 + tc * 16 + quad * 4;
            float x[4];
#pragma unroll
            for (int r = 0; r < 4; ++r) {
                float v = acc[tr][tc][r];
                if (EPI >= 1) v += bv[tc][r];
                if (EPI == 2) v = fast_gelu(v);
                x[r] = v;
            }
            uint2 pk;
            pk.x = (unsigned)f2b(x[0]) | ((unsigned)f2b(x[1]) << 16);
            pk.y = (unsigned)f2b(x[2]) | ((unsigned)f2b(x[3]) << 16);
            *(uint2*)(C + (size_t)grow * ldc + gcb) = pk;
        }
    }
}

// ---------------- r13 8-phase 256x256 GEMM (QKV, FF1) ----------------
// 512 thr / 8 waves (wr=wid>>2 in {0,1}, wc=wid&3). Per-wave C: 128x64.
// LDS: A/B tiles [256][64] bf16, double-buffered (128KB). K-tile = 64.
// Half-tiles: h0=A rows 0-127, h1=A rows 128-255, h2=B 0-127, h3=B 128-255.
// Lead-5 staging: phase g stages half g+5. Boundary wait vmcnt(2) (FIFO ->
// all 4 needed halves forced complete; 1 half stays in flight). Swizzle:
// physical chunk c of row r holds global chunk c^(r&7) (pre-swizzled source).
template<int EPI>
__global__ __launch_bounds__(512, 2)
void mfma_gemm256(const ushort_t* __restrict__ A, int lda,
                  const ushort_t* __restrict__ Bt, int ldb,
                  const void* __restrict__ biasv, size_t biasoff,
                  ushort_t* __restrict__ C, int ldc,
                  const unsigned int* __restrict__ dtp, int N, int K) {
    __shared__ ushort_t As[2][256 * 64];
    __shared__ ushort_t Bs[2][256 * 64];
    const int tid = threadIdx.x;
    const int nwg = gridDim.x * gridDim.y;
    const int wg  = blockIdx.y * gridDim.x + blockIdx.x;
    const int cpx = nwg >> 3;
    const int swz = (wg & 7) * cpx + (wg >> 3);
    const int bm = (swz / gridDim.y) * 256;
    const int bn = (swz % gridDim.y) * 256;
    const int wid = tid >> 6, lane = tid & 63;
    const int wr = wid >> 2, wc = wid & 3;
    const int quad = lane >> 4, l16 = lane & 15;
    const int l7 = l16 & 7;

    // staging constants: thread covers rows (tid>>3) and 64+(tid>>3), chunk tid&7
    const int srow = tid >> 3;
    const int sch  = (tid & 7) ^ (srow & 7);     // 64 = 0 mod 8 -> same for round 1
    const int ldsoff0 = tid * 8, ldsoff1 = (512 + tid) * 8;

#define STAGE256(X) do {                                                       \
        int ts_ = (X) >> 2, j2_ = (X) & 3, b_ = ts_ & 1;                       \
        if (j2_ < 2) {                                                         \
            const ushort_t* g0 = A + (size_t)(bm + j2_ * 128 + srow) * lda     \
                                 + ts_ * 64 + sch * 8;                         \
            async16(g0,             As[b_] + j2_ * 8192 + ldsoff0);            \
            async16(g0 + 64 * lda,  As[b_] + j2_ * 8192 + ldsoff1);            \
        } else {                                                               \
            const ushort_t* g0 = Bt + (size_t)(bn + (j2_ - 2) * 128 + srow) * ldb \
                                 + ts_ * 64 + sch * 8;                         \
            async16(g0,             Bs[b_] + (j2_ - 2) * 8192 + ldsoff0);      \
            async16(g0 + 64 * ldb,  Bs[b_] + (j2_ - 2) * 8192 + ldsoff1);      \
        }                                                                      \
    } while (0)

    f32x4 acc[8][4];
#pragma unroll
    for (int i = 0; i < 8; ++i)
#pragma unroll
        for (int j = 0; j < 4; ++j)
#pragma unroll
            for (int r = 0; r < 4; ++r) acc[i][j][r] = 0.f;

    const int NT = K >> 6;
    // prologue: tile0 (h0-h3) + tile1 h0; halves 0-3 forced complete.
    STAGE256(0); STAGE256(1); STAGE256(2); STAGE256(3); STAGE256(4);
    asm volatile("s_waitcnt vmcnt(2)" ::: "memory");
    __builtin_amdgcn_s_barrier();

    // per-thread read bases
    const int arow = wr * 128 + l16;        // + fm*16
    const int brow = wc * 64 + l16;         // + ni*16
    const int chq0 = (quad ^ l7) * 8;             // ks=0 chunk byte-elems
    const int chq1 = ((4 + quad) ^ l7) * 8;       // ks=1

    short8 af[4][2], bf[4][2];
    for (int kt = 0; kt < NT; ++kt) {
        const ushort_t* Ab = As[kt & 1];
        const ushort_t* Bb = Bs[kt & 1];
#pragma unroll
        for (int j = 0; j < 4; ++j) {
            const int rh = j >> 1, nh = j & 1;
            if (j == 0) {
#pragma unroll
                for (int m = 0; m < 4; ++m) {
                    const ushort_t* rp = Ab + (arow + m * 16) * 64;
                    af[m][0] = *(const short8*)(rp + chq0);
                    af[m][1] = *(const short8*)(rp + chq1);
                }
#pragma unroll
                for (int n2 = 0; n2 < 2; ++n2) {
                    const ushort_t* rp = Bb + (brow + n2 * 16) * 64;
                    bf[n2][0] = *(const short8*)(rp + chq0);
                    bf[n2][1] = *(const short8*)(rp + chq1);
                }
            } else if (j == 1) {
#pragma unroll
                for (int n2 = 0; n2 < 2; ++n2) {
                    const ushort_t* rp = Bb + (brow + (2 + n2) * 16) * 64;
                    bf[2 + n2][0] = *(const short8*)(rp + chq0);
                    bf[2 + n2][1] = *(const short8*)(rp + chq1);
                }
            } else if (j == 2) {
#pragma unroll
                for (int m = 0; m < 4; ++m) {
                    const ushort_t* rp = Ab + (arow + 64 + m * 16) * 64;
                    af[m][0] = *(const short8*)(rp + chq0);
                    af[m][1] = *(const short8*)(rp + chq1);
                }
            }
            int hg = kt * 4 + j + 5;
            if (hg < NT * 4) STAGE256(hg);
            __builtin_amdgcn_s_barrier();
            __builtin_amdgcn_s_setprio(1);
#pragma unroll
            for (int m = 0; m < 4; ++m)
#pragma unroll
                for (int n2 = 0; n2 < 2; ++n2) {
                    f32x4 a = acc[rh * 4 + m][nh * 2 + n2];
                    a = __builtin_amdgcn_mfma_f32_16x16x32_bf16(bf[nh * 2 + n2][0], af[m][0], a, 0, 0, 0);
                    a = __builtin_amdgcn_mfma_f32_16x16x32_bf16(bf[nh * 2 + n2][1], af[m][1], a, 0, 0, 0);
                    acc[rh * 4 + m][nh * 2 + n2] = a;
                }
            __builtin_amdgcn_s_setprio(0);
            if (j == 3 && kt + 1 < NT) {
                if (kt + 3 < NT) asm volatile("s_waitcnt vmcnt(2)" ::: "memory");
                else             asm volatile("s_waitcnt vmcnt(0)" ::: "memory");
            }
            __builtin_amdgcn_s_barrier();
        }
    }
#undef STAGE256

    const bool isbf = (dtp[0] != FP32_ONE);
    float bv[4][4];
    if (EPI >= 1) {
#pragma unroll
        for (int ni = 0; ni < 4; ++ni)
#pragma unroll
            for (int r = 0; r < 4; ++r)
                bv[ni][r] = ldx(biasv, biasoff + bn + wc * 64 + ni * 16 + quad * 4 + r, isbf);
    }
    (void)N;
#pragma unroll
    for (int mi = 0; mi < 8; ++mi) {
        int grow = bm + wr * 128 + mi * 16 + l16;
#pragma unroll
        for (int ni = 0; ni < 4; ++ni) {
            int gcb = bn + wc * 64 + ni * 16 + quad * 4;
            float x[4];
#pragma unroll
            for (int r = 0; r < 4; ++r) {
                float v = acc[mi][ni][r];
                if (EPI >= 1) v += bv[ni][r];
                if (EPI == 2) v = fast_gelu(v);
                x[r] = v;
            }
            uint2 pk;
            pk.x = (unsigned)f2b(x[0]) | ((unsigned)f2b(x[1]) << 16);
            pk.y = (unsigned)f2b(x[2]) | ((unsigned)f2b(x[3]) << 16);
            *(uint2*)(C + (size_t)grow * ldc + gcb) = pk;
        }
    }
}

// MFMA banded attention; PV uses swapped operands (packed 8B output stores).
// LDS XOR chunk-swizzle (r10): Ks/Rs chunk q of row r at (q ^ (r&7));
// VT/Ps chunk q of row r at (q ^ (r&15)). Same on write and read.
__global__ __launch_bounds__(256) void attn_mfma(
    ushort_t* __restrict__ qkv, const ushort_t* __restrict__ krb,
    const void* __restrict__ rwb, const void* __restrict__ rrb, size_t boff,
    const void* __restrict__ im,
    const unsigned int* __restrict__ dtp) {
    const bool isbf = (dtp[0] != FP32_ONE);
    __shared__ ushort_t Ks[128 * 64];
    __shared__ ushort_t VT[64 * 128];
    __shared__ ushort_t Rs[64 * 64];
    __shared__ float    BD2[4 * 16 * 64];
    __shared__ ushort_t Ps[4 * 16 * 128];
    __shared__ float    imk[128];
    __shared__ float    imq[64];

    const int tid = threadIdx.x;
    const int i0 = blockIdx.x * 64;
    const int b  = blockIdx.y;
    const int n  = blockIdx.z;
    const int o  = OMEGA_C[n];
    const int noff = n * DH;
    const int j0 = i0 - 64;
    const int w = tid >> 6, lane = tid & 63;
    const int quad = lane >> 4, l16 = lane & 15;

#pragma unroll
    for (int it = 0; it < 4; ++it) {
        int q4 = it * 256 + tid;
        int c  = q4 >> 3, ch = q4 & 7;
        int jc = j0 + c; jc = jc < 0 ? 0 : jc;
        size_t rowb = (size_t)(jc * B_ + b) * QKV_LD + noff;
        *(uint4*)(Ks + c * 64 + ((ch ^ (c & 7)) << 3)) = *(const uint4*)(qkv + rowb + 512 + ch * 8);
        ushort_t v8[8];
        *(uint4*)v8 = *(const uint4*)(qkv + rowb + 1024 + ch * 8);
#pragma unroll
        for (int e = 0; e < 8; ++e) {
            int vr = ch * 8 + e;
            VT[vr * 128 + (((c >> 3) ^ (vr & 15)) << 3) + (c & 7)] = v8[e];
        }
    }
#pragma unroll
    for (int it = 0; it < 2; ++it) {
        int q4 = it * 256 + tid;
        int m = q4 >> 3, ch = q4 & 7;
        *(uint4*)(Rs + m * 64 + ((ch ^ (m & 7)) << 3)) =
            *(const uint4*)(krb + (size_t)(512 - m) * 512 + noff + ch * 8);
    }
    if (tid < 128) {
        int j = j0 + tid;
        imk[tid] = (j >= 0) ? ldx(im, b * S_ + j, isbf) : 0.f;
    } else if (tid < 192) {
        imq[tid - 128] = ldx(im, b * S_ + i0 + (tid - 128), isbf);
    }
    __syncthreads();

    const int qrow = i0 + w * 16 + l16;
    size_t qbase = (size_t)(qrow * B_ + b) * QKV_LD + noff;
    short8 aw[2], ar[2];
#pragma unroll
    for (int kc = 0; kc < 2; ++kc) {
        int kof = kc * 32 + quad * 8;
        ushort_t qe[8];
        *(uint4*)qe = *(const uint4*)(qkv + qbase + kof);
#pragma unroll
        for (int e = 0; e < 8; ++e) {
            float f = b2f(qe[e]);
            ((ushort_t*)&aw[kc])[e] = f2b(f + ldx(rwb, boff + noff + kof + e, isbf));
            ((ushort_t*)&ar[kc])[e] = f2b(f + ldx(rrb, boff + noff + kof + e, isbf));
        }
    }

    f32x4 accs[8];
#pragma unroll
    for (int ct = 0; ct < 8; ++ct) {
        int kr = ct * 16 + l16;
        short8 b0 = *(const short8*)(Ks + kr * 64 + ((quad ^ (kr & 7)) << 3));
        short8 b1 = *(const short8*)(Ks + kr * 64 + (((quad + 4) ^ (kr & 7)) << 3));
        f32x4 z = {0.f, 0.f, 0.f, 0.f};
        z = __builtin_amdgcn_mfma_f32_16x16x32_bf16(aw[0], b0, z, 0, 0, 0);
        z = __builtin_amdgcn_mfma_f32_16x16x32_bf16(aw[1], b1, z, 0, 0, 0);
        accs[ct] = z;
    }
    float* BD2w = BD2 + w * 16 * 64;
#pragma unroll
    for (int mt = 0; mt < 4; ++mt) {
        int rr = mt * 16 + l16;
        short8 b0 = *(const short8*)(Rs + rr * 64 + ((quad ^ (rr & 7)) << 3));
        short8 b1 = *(const short8*)(Rs + rr * 64 + (((quad + 4) ^ (rr & 7)) << 3));
        f32x4 z = {0.f, 0.f, 0.f, 0.f};
        z = __builtin_amdgcn_mfma_f32_16x16x32_bf16(ar[0], b0, z, 0, 0, 0);
        z = __builtin_amdgcn_mfma_f32_16x16x32_bf16(ar[1], b1, z, 0, 0, 0);
#pragma unroll
        for (int r = 0; r < 4; ++r)
            BD2w[(quad * 4 + r) * 64 + mt * 16 + l16] = z[r];
    }

    float im_i[4];
#pragma unroll
    for (int r = 0; r < 4; ++r) im_i[r] = imq[w * 16 + quad * 4 + r];

    float sc[8][4];
#pragma unroll
    for (int ct = 0; ct < 8; ++ct) {
        int cl = ct * 16 + l16;
        float imk_c = imk[cl];
#pragma unroll
        for (int r = 0; r < 4; ++r) {
            int qrl = w * 16 + quad * 4 + r;
            int rel = qrl + 64 - cl;
            int relc = rel < 0 ? 0 : (rel > 63 ? 63 : rel);
            float bd = BD2w[(quad * 4 + r) * 64 + relc];
            bool valid = (rel >= 0) && (rel < o) && (rel <= i0 + qrl)
                         && (im_i[r] + imk_c <= 0.f);
            sc[ct][r] = valid ? (accs[ct][r] + bd) * 0.125f : -1e30f;
        }
    }
    float rl[4];
#pragma unroll
    for (int r = 0; r < 4; ++r) {
        float mx = sc[0][r];
#pragma unroll
        for (int ct = 1; ct < 8; ++ct) mx = fmaxf(mx, sc[ct][r]);
        mx = row16_max(mx);
        float l = 0.f;
#pragma unroll
        for (int ct = 0; ct < 8; ++ct) {
            float pv = __expf(sc[ct][r] - mx);
            sc[ct][r] = pv;
            l += pv;
        }
        l = row16_sum(l);
        rl[r] = 1.f / l;
    }
    ushort_t* Pw = Ps + w * 16 * 128;
#pragma unroll
    for (int ct = 0; ct < 8; ++ct)
#pragma unroll
        for (int r = 0; r < 4; ++r) {
            int prow = quad * 4 + r;
            Pw[prow * 128 + ((((ct * 2 + (l16 >> 3)) ^ prow) & 15) << 3) + (l16 & 7)]
                = f2b(sc[ct][r] * rl[r]);
        }

    short8 aP[4];
#pragma unroll
    for (int kc = 0; kc < 4; ++kc)
        aP[kc] = *(const short8*)(Pw + l16 * 128 + ((((kc * 4 + quad) ^ l16) & 15) << 3));

    const int qg = i0 + w * 16 + l16;
    const size_t obase = (size_t)(qg * B_ + b) * QKV_LD + noff;
#pragma unroll
    for (int dt = 0; dt < 4; ++dt) {
        f32x4 accT = {0.f, 0.f, 0.f, 0.f};
#pragma unroll
        for (int kc = 0; kc < 4; ++kc) {
            int vrow = dt * 16 + l16;
            short8 bV = *(const short8*)(VT + vrow * 128 + ((((kc * 4 + quad) ^ (vrow & 15)) & 15) << 3));
            accT = __builtin_amdgcn_mfma_f32_16x16x32_bf16(bV, aP[kc], accT, 0, 0, 0);
        }
        uint2 pk;
        pk.x = (unsigned)f2b(accT[0]) | ((unsigned)f2b(accT[1]) << 16);
        pk.y = (unsigned)f2b(accT[2]) | ((unsigned)f2b(accT[3]) << 16);
        *(uint2*)(qkv + obase + dt * 16 + quad * 4) = pk;
    }
}

// h = LayerNorm(x + h)*w + b. Wave-per-row, uint4, no barriers.
__global__ __launch_bounds__(256) void add_ln_kernel(
    const ushort_t* __restrict__ x, ushort_t* __restrict__ h,
    const void* __restrict__ w, const void* __restrict__ b, size_t boff,
    const unsigned int* __restrict__ dtp) {
    const bool isbf = (dtp[0] != FP32_ONE);
    int lane = threadIdx.x & 63;
    int row = blockIdx.x * 4 + (threadIdx.x >> 6);
    size_t base = (size_t)row * D_ + lane * 8;
    ushort_t xe[8], he[8];
    *(uint4*)xe = *(const uint4*)(x + base);
    *(uint4*)he = *(const uint4*)(h + base);
    float v[8];
    float s = 0.f, ss = 0.f;
#pragma unroll
    for (int e = 0; e < 8; ++e) {
        v[e] = b2f(xe[e]) + b2f(he[e]);
        s += v[e]; ss += v[e] * v[e];
    }
    dpp_sum64(s); dpp_sum64(ss);
    float S = rlane(s, 63), SS = rlane(ss, 63);
    float mu  = S * (1.f / D_);
    float var = fmaxf(SS * (1.f / D_) - mu * mu, 0.f);
    float inv = rsqrtf(var + 1e-8f);
    ushort_t oe[8];
#pragma unroll
    for (int e = 0; e < 8; ++e)
        oe[e] = f2b((v[e] - mu) * inv * ldx(w, boff + lane * 8 + e, isbf)
                    + ldx(b, boff + lane * 8 + e, isbf));
    *(uint4*)(h + base) = *(uint4*)oe;
}

__global__ __launch_bounds__(256) void writeout_kernel(const ushort_t* __restrict__ h,
                                                       void* __restrict__ out,
                                                       const unsigned int* __restrict__ dtp) {
    const bool isbf = (dtp[0] != FP32_ONE);
    int idx = blockIdx.x * 256 + threadIdx.x;        // over M_*D_/8
    int d8 = idx & 63;
    int rest = idx >> 6;                             // b*S + s
    int s = rest & (S_ - 1), b = rest >> 9;
    ushort_t ve[8];
    *(uint4*)ve = *(const uint4*)(h + ((size_t)(s * B_ + b) << 9) + d8 * 8);
    if (isbf) {
        *(uint4*)((ushort_t*)out + (size_t)idx * 8) = *(uint4*)ve;
    } else {
        float* op = (float*)out + (size_t)idx * 8;
        ((float4*)op)[0] = make_float4(b2f(ve[0]), b2f(ve[1]), b2f(ve[2]), b2f(ve[3]));
        ((float4*)op)[1] = make_float4(b2f(ve[4]), b2f(ve[5]), b2f(ve[6]), b2f(ve[7]));
    }
}

extern "C" void kernel_launch(void* const* d_in, const int* in_sizes, int n_in,
                              void* d_out, int out_size, void* d_ws, size_t ws_size,
                              hipStream_t stream) {
    (void)in_sizes; (void)n_in; (void)out_size; (void)ws_size;
    const int*  ids = (const int*)d_in[0];
    const void* im  = d_in[1];
    const void* emb = d_in[2];
    const void* Wq = d_in[3], *Wk = d_in[4], *Wv = d_in[5], *Wr = d_in[6], *Wo = d_in[7];
    const void* rrb = d_in[8], *rwb = d_in[9];
    const void* lnaw = d_in[10], *lnab = d_in[11];
    const void* W1 = d_in[12], *b1 = d_in[13], *W2 = d_in[14], *b2 = d_in[15];
    const void* lnfw = d_in[16], *lnfb = d_in[17];
    const unsigned int* dtp = (const unsigned int*)d_in[10];  // dtype probe

    // ---- workspace layout, ~160 MB ----
    char* wsb = (char*)d_ws;
    ushort_t* h    = (ushort_t*)wsb;                   // [0,16)    bf16 16384x512
    ushort_t* qkv  = (ushort_t*)(wsb + (16u << 20));   // [16,64)   bf16 16384x1536
    ushort_t* tmp  = (ushort_t*)(wsb + (64u << 20));   // [64,80)   bf16 16384x512
    ushort_t* ff1  = (ushort_t*)(wsb + (80u << 20));   // [80,144)  bf16 16384x2048
    ushort_t* wbuf = (ushort_t*)(wsb + (144u << 20));  // [144,157) weights
    ushort_t* posb = (ushort_t*)(wsb + (157u << 20));  // [157,158) bf16 1024x512
    ushort_t* krb0 = (ushort_t*)(wsb + (158u << 20));  // [158,159) bf16 1024x512
    ushort_t* krb1 = (ushort_t*)(wsb + (159u << 20));  // [159,160)

    embed_kernel<<<4096, 256, 0, stream>>>(ids, emb, h, dtp);
    posemb_kernel<<<1024, 256, 0, stream>>>(posb);

    transp_cvt4<<<dim3(16, 16, 8), 256, 0, stream>>>(Wq, Wk, Wv, Wr, wbuf, dtp);
    cvtL<<<dim3(1024, 1, 2), 256, 0, stream>>>(Wo, 262144, wbuf, 1048576, dtp, 262144);
    transp_cvtL<<<dim3(64, 16, 2), 256, 0, stream>>>(W1, 1048576, wbuf, 1310720, dtp, 512, 2048);
    transp_cvtL<<<dim3(16, 64, 2), 256, 0, stream>>>(W2, 1048576, wbuf, 2359296, dtp, 2048, 512);

    // k_r for both layers upfront
    mfma_gemm<0><<<dim3(8, 4), 256, 0, stream>>>(posb, 512, wbuf + 786432, 512, nullptr, 0, krb0, 512, dtp, 1024, 512, 512);
    mfma_gemm<0><<<dim3(8, 4), 256, 0, stream>>>(posb, 512, wbuf + WL + 786432, 512, nullptr, 0, krb1, 512, dtp, 1024, 512, 512);

    for (int l = 0; l < 2; ++l) {
        size_t boff = (size_t)l * 512;
        size_t b1off = (size_t)l * 2048;
        ushort_t* qkvT = wbuf + (size_t)l * WL;
        ushort_t* woc  = qkvT + 1048576;
        ushort_t* w1T  = woc  + 262144;
        ushort_t* w2T  = w1T  + 1048576;
        ushort_t* krb  = l ? krb1 : krb0;

        // fused q|k|v = h @ [Wq|Wk|Wv] (16384x1536): 8-phase 256² kernel
        mfma_gemm256<0><<<dim3(64, 6), 512, 0, stream>>>(h, 512, qkvT, 512, nullptr, 0, qkv, QKV_LD, dtp, QKV_LD, 512);

        attn_mfma<<<dim3(8, 32, 8), 256, 0, stream>>>(qkv, krb, rwb, rrb, boff, im, dtp);

        // attn_out = av @ Wo^T (av in q slots, lda=1536)
        mfma_gemm<0><<<dim3(128, 4), 256, 0, stream>>>(qkv, QKV_LD, woc, 512, nullptr, 0, tmp, 512, dtp, M_, 512, 512);
        add_ln_kernel<<<4096, 256, 0, stream>>>(tmp, h, lnaw, lnab, boff, dtp);

        // FFN: FF1 (N=2048) on 8-phase 256², FF2 (K=2048) on 128²
        mfma_gemm256<2><<<dim3(64, 8), 512, 0, stream>>>(h, 512, w1T, 512, b1, b1off, ff1, DI, dtp, DI, 512);
        mfma_gemm<1><<<dim3(128, 4),  256, 0, stream>>>(ff1, DI, w2T, 2048, b2, boff, tmp, 512, dtp, M_, 512, DI);
        add_ln_kernel<<<4096, 256, 0, stream>>>(tmp, h, lnfw, lnfb, boff, dtp);
    }

    writeout_kernel<<<4096, 256, 0, stream>>>(h, d_out, dtp);
}

// Round 5
// 756.142 us; speedup vs baseline: 1.0210x; 1.0210x over previous
//
#include <hip/hip_runtime.h>
#include <math.h>

// DualRec 2-layer transformer-XL model, MI355X — round 14.
// r14: r13's 8-phase 256² REGRESSED (FF1 96µs, 1 block/CU @128KB LDS, NT=8
// too short for the pipeline regime) -> reverted to r12 128² triple-buffer
// counted-vmcnt GEMM everywhere. New this round:
//   (a) krb GEMMs for both layers merged into ONE dispatch (grid z=2,
//       B/C z-strides) — same-stream kernels never overlap, saves ~10µs.
//   (b) attn_mfma XCD-aware block remap (T1): each XCD owns 4 batches
//       (b = (bid&7)*4 + slot>>6, i0 fastest) so overlapping K/V windows
//       and per-b qkv panels stay L2-resident per XCD.
// Carried: r12 triple-buffer counted-vmcnt 128² GEMM (3 blocks/CU), r11
// bn-fastest XCD swizzle + A&S erf GELU, r10 attn LDS XOR swizzle + __expf.

#define S_  512
#define B_  32
#define D_  512
#define NH  8
#define DH  64
#define DI  2048
#define M_  (S_*B_)
#define QKV_LD 1536
#define WL  3407872   // per-layer wbuf elements (6.5 MiB)
#define FP32_ONE 0x3F800000u

typedef unsigned short ushort_t;
typedef __attribute__((ext_vector_type(8))) short short8;
typedef __attribute__((ext_vector_type(4))) float f32x4;

__constant__ int OMEGA_C[8] = {2, 3, 4, 5, 7, 11, 21, 50};

__device__ __forceinline__ float b2f(ushort_t us) {
    return __uint_as_float(((unsigned int)us) << 16);
}
__device__ __forceinline__ ushort_t f2b(float f) {
    unsigned int u = __float_as_uint(f);
    return (ushort_t)((u + 0x7fffu + ((u >> 16) & 1u)) >> 16);
}
__device__ __forceinline__ float ldx(const void* p, size_t idx, bool isbf) {
    return isbf ? b2f(((const ushort_t*)p)[idx]) : ((const float*)p)[idx];
}
__device__ __forceinline__ void async16(const ushort_t* g, ushort_t* l) {
    __builtin_amdgcn_global_load_lds(
        (const __attribute__((address_space(1))) unsigned int*)g,
        (__attribute__((address_space(3))) unsigned int*)l, 16, 0, 0);
}

// Branch-free exact-GELU: 0.5*v*(1+erf(v/sqrt2)) via A&S 7.1.26 (|err|<=1.5e-7).
__device__ __forceinline__ float fast_gelu(float v) {
    float x  = v * 0.7071067811865475f;
    float ax = fabsf(x);
    float t  = __builtin_amdgcn_rcpf(fmaf(0.3275911f, ax, 1.f));
    float p  = fmaf(fmaf(fmaf(fmaf(1.061405429f, t, -1.453152027f),
                              t, 1.421413741f),
                         t, -0.284496736f),
                    t, 0.254829592f) * t;
    float e    = __expf(-ax * ax);
    float erfa = fmaf(-p, e, 1.f);          // erf(|x|)
    float erfx = copysignf(erfa, x);
    return 0.5f * v * (1.f + erfx);
}

// ---- DPP reductions ----
#define DPPA(v, ctrl) v += __int_as_float(__builtin_amdgcn_update_dpp(0, __float_as_int(v), ctrl, 0xf, 0xf, true))
__device__ __forceinline__ void dpp_sum64(float& v) {
    DPPA(v, 0x111); DPPA(v, 0x112); DPPA(v, 0x114);
    DPPA(v, 0x118); DPPA(v, 0x142); DPPA(v, 0x143);
}
#define DPPROR(v, ctrl) __int_as_float(__builtin_amdgcn_update_dpp(__float_as_int(v), __float_as_int(v), ctrl, 0xf, 0xf, false))
__device__ __forceinline__ float row16_sum(float v) {
    v += DPPROR(v, 0x128); v += DPPROR(v, 0x124);
    v += DPPROR(v, 0x122); v += DPPROR(v, 0x121);
    return v;
}
__device__ __forceinline__ float row16_max(float v) {
    v = fmaxf(v, DPPROR(v, 0x128)); v = fmaxf(v, DPPROR(v, 0x124));
    v = fmaxf(v, DPPROR(v, 0x122)); v = fmaxf(v, DPPROR(v, 0x121));
    return v;
}
__device__ __forceinline__ float rlane(float v, int l) {
    return __int_as_float(__builtin_amdgcn_readlane(__float_as_int(v), l));
}

__global__ __launch_bounds__(256) void embed_kernel(const int* __restrict__ ids,
                                                    const void* __restrict__ emb,
                                                    ushort_t* __restrict__ h,
                                                    const unsigned int* __restrict__ dtp) {
    const bool isbf = (dtp[0] != FP32_ONE);
    int idx = blockIdx.x * 256 + threadIdx.x;        // over M_*D_/8
    int d8 = idx & 63;
    int row = idx >> 6;                              // i*B + b
    int s = row >> 5, b = row & 31;
    int id = ids[b * S_ + s];
    size_t src = (size_t)id * D_ + d8 * 8;
    if (isbf) {
        *(uint4*)(h + (size_t)row * D_ + d8 * 8) = *(const uint4*)((const ushort_t*)emb + src);
    } else {
        const float* e = (const float*)emb + src;
        float4 a0 = ((const float4*)e)[0], a1 = ((const float4*)e)[1];
        uint4 pk;
        pk.x = (unsigned)f2b(a0.x) | ((unsigned)f2b(a0.y) << 16);
        pk.y = (unsigned)f2b(a0.z) | ((unsigned)f2b(a0.w) << 16);
        pk.z = (unsigned)f2b(a1.x) | ((unsigned)f2b(a1.y) << 16);
        pk.w = (unsigned)f2b(a1.z) | ((unsigned)f2b(a1.w) << 16);
        *(uint4*)(h + (size_t)row * D_ + d8 * 8) = pk;
    }
}

__global__ __launch_bounds__(256) void posemb_kernel(ushort_t* __restrict__ pos) {
    int flat = blockIdx.x * 256 + threadIdx.x;       // over 1024*256
    int p = flat >> 8, k = flat & 255;
    float inv = expf((float)k * -0.035977892078031f);
    float val = (512.0f - (float)p) * inv;
    pos[p * D_ + k]       = f2b(sinf(val));
    pos[p * D_ + 256 + k] = f2b(cosf(val));
}

__global__ __launch_bounds__(256) void transp_cvt4(
    const void* __restrict__ s0, const void* __restrict__ s1,
    const void* __restrict__ s2, const void* __restrict__ s3,
    ushort_t* __restrict__ wbuf, const unsigned int* __restrict__ dtp) {
    const bool isbf = (dtp[0] != FP32_ONE);
    __shared__ float tt[32][33];
    int z = blockIdx.z, layer = z >> 2, t4 = z & 3;
    const void* srcs[4] = {s0, s1, s2, s3};
    const void* in = srcs[t4];
    size_t inoff = (size_t)layer * 262144;
    ushort_t* out = wbuf + (size_t)layer * WL + (size_t)t4 * 262144;
    int tx = threadIdx.x & 31, ty = threadIdx.x >> 5;
    int n0 = blockIdx.x * 32, k0 = blockIdx.y * 32;
#pragma unroll
    for (int it = 0; it < 4; ++it)
        tt[ty + it * 8][tx] = ldx(in, inoff + (size_t)(k0 + ty + it * 8) * 512 + n0 + tx, isbf);
    __syncthreads();
#pragma unroll
    for (int it = 0; it < 4; ++it)
        out[(size_t)(n0 + ty + it * 8) * 512 + k0 + tx] = f2b(tt[tx][ty + it * 8]);
}

__global__ __launch_bounds__(256) void transp_cvtL(const void* __restrict__ in, size_t perlin,
                                                   ushort_t* __restrict__ wbuf, size_t outoff,
                                                   const unsigned int* __restrict__ dtp,
                                                   int K, int N) {
    const bool isbf = (dtp[0] != FP32_ONE);
    __shared__ float tt[32][33];
    int layer = blockIdx.z;
    size_t inoff = (size_t)layer * perlin;
    ushort_t* out = wbuf + (size_t)layer * WL + outoff;
    int tx = threadIdx.x & 31, ty = threadIdx.x >> 5;
    int n0 = blockIdx.x * 32, k0 = blockIdx.y * 32;
#pragma unroll
    for (int it = 0; it < 4; ++it)
        tt[ty + it * 8][tx] = ldx(in, inoff + (size_t)(k0 + ty + it * 8) * N + n0 + tx, isbf);
    __syncthreads();
#pragma unroll
    for (int it = 0; it < 4; ++it)
        out[(size_t)(n0 + ty + it * 8) * K + k0 + tx] = f2b(tt[tx][ty + it * 8]);
}

__global__ __launch_bounds__(256) void cvtL(const void* __restrict__ in, size_t perlin,
                                            ushort_t* __restrict__ wbuf, size_t outoff,
                                            const unsigned int* __restrict__ dtp, int nelem) {
    const bool isbf = (dtp[0] != FP32_ONE);
    int layer = blockIdx.z;
    int i = blockIdx.x * 256 + threadIdx.x;
    if (i < nelem)
        wbuf[(size_t)layer * WL + outoff + i] = f2b(ldx(in, (size_t)layer * perlin + i, isbf));
}

// C[M,N] = A[M,K](bf16, lda) x B^T[n][k](bf16, ldb).
// EPI: 0 none, 1 +bias, 2 +bias+exact GELU. Swapped-operand MFMA: lane owns
// C[row l16][4 consecutive cols] -> 8B packed bf16 stores.
// Triple-buffered counted-vmcnt K-loop (r12): tile t+2 issued each iteration,
// vmcnt(8) keeps 2 tiles in flight across the barrier. bzoff/czoff: optional
// per-blockIdx.z strides on B/C (lets independent GEMMs share one dispatch).
template<int EPI>
__global__ __launch_bounds__(256)
void mfma_gemm(const ushort_t* __restrict__ A, int lda,
               const ushort_t* __restrict__ Bt, int ldb,
               const void* __restrict__ biasv, size_t biasoff,
               ushort_t* __restrict__ C, int ldc,
               size_t bzoff, size_t czoff,
               const unsigned int* __restrict__ dtp, int M, int N, int K) {
    const bool isbf = (dtp[0] != FP32_ONE);
    __shared__ ushort_t As[3][128 * 32];
    __shared__ ushort_t Bs[3][128 * 32];
    const int tid = threadIdx.x;
    Bt += (size_t)blockIdx.z * bzoff;
    C  += (size_t)blockIdx.z * czoff;
    // XCD swizzle (nwg % 8 == 0 at all call sites): contiguous swz chunk per
    // XCD; within the chunk bn varies fastest (B panel L2-resident).
    const int nwg = gridDim.x * gridDim.y;
    const int wg  = blockIdx.y * gridDim.x + blockIdx.x;
    const int cpx = nwg >> 3;
    const int swz = (wg & 7) * cpx + (wg >> 3);
    const int bm = (swz / gridDim.y) * 128;
    const int bn = (swz % gridDim.y) * 128;
    const int w = tid >> 6, lane = tid & 63;
    const int wr = w >> 1, wc = w & 1;
    const int quad = lane >> 4, l16 = lane & 15;
    const int rsub = lane >> 2;
    const int kcg  = (lane & 3) ^ ((rsub >> 1) & 3);
    const int fsw  = (l16 >> 1) & 3;

    const ushort_t* ga0 = A  + (size_t)(bm + w * 16 + rsub) * lda + kcg * 8;
    const ushort_t* ga1 = A  + (size_t)(bm + (4 + w) * 16 + rsub) * lda + kcg * 8;
    const ushort_t* gb0 = Bt + (size_t)(bn + w * 16 + rsub) * ldb + kcg * 8;
    const ushort_t* gb1 = Bt + (size_t)(bn + (4 + w) * 16 + rsub) * ldb + kcg * 8;

#define STAGE_T(kt, bi) do {                                  \
        int _k0 = (kt) << 5;                                  \
        async16(ga0 + _k0, As[bi] + w * 512);                 \
        async16(gb0 + _k0, Bs[bi] + w * 512);                 \
        async16(ga1 + _k0, As[bi] + (4 + w) * 512);           \
        async16(gb1 + _k0, Bs[bi] + (4 + w) * 512);           \
    } while (0)

    f32x4 acc[4][4];
#pragma unroll
    for (int i = 0; i < 4; ++i)
#pragma unroll
        for (int j = 0; j < 4; ++j)
#pragma unroll
            for (int r = 0; r < 4; ++r) acc[i][j][r] = 0.f;

    const int nt = K >> 5;
    STAGE_T(0, 0);
    STAGE_T(1, 1);
    int cur = 0, nxt = 2;
    for (int t = 0; t < nt; ++t) {
        if (t + 2 < nt) {
            STAGE_T(t + 2, nxt);
            asm volatile("s_waitcnt vmcnt(8)" ::: "memory");
        } else if (t + 1 < nt) {
            asm volatile("s_waitcnt vmcnt(4)" ::: "memory");
        } else {
            asm volatile("s_waitcnt vmcnt(0)" ::: "memory");
        }
        __builtin_amdgcn_s_barrier();
        asm volatile("" ::: "memory");

        short8 af[4], bf[4];
#pragma unroll
        for (int tt = 0; tt < 4; ++tt) {
            int ra = wr * 64 + tt * 16 + l16;
            int rb = wc * 64 + tt * 16 + l16;
            af[tt] = *(const short8*)(As[cur] + ra * 32 + ((quad ^ fsw) * 8));
            bf[tt] = *(const short8*)(Bs[cur] + rb * 32 + ((quad ^ fsw) * 8));
        }
#pragma unroll
        for (int tr = 0; tr < 4; ++tr)
#pragma unroll
            for (int tc = 0; tc < 4; ++tc)
                acc[tr][tc] = __builtin_amdgcn_mfma_f32_16x16x32_bf16(bf[tc], af[tr], acc[tr][tc], 0, 0, 0);

        asm volatile("s_waitcnt lgkmcnt(0)" ::: "memory");
        __builtin_amdgcn_s_barrier();
        cur = cur == 2 ? 0 : cur + 1;
        nxt = nxt == 2 ? 0 : nxt + 1;
    }
#undef STAGE_T

    float bv[4][4];
    if (EPI >= 1) {
#pragma unroll
        for (int tc = 0; tc < 4; ++tc)
#pragma unroll
            for (int r = 0; r < 4; ++r)
                bv[tc][r] = ldx(biasv, biasoff + bn + wc * 64 + tc * 16 + quad * 4 + r, isbf);
    }
#pragma unroll
    for (int tr = 0; tr < 4; ++tr) {
        int grow = bm + wr * 64 + tr * 16 + l16;
#pragma unroll
        for (int tc = 0; tc < 4; ++tc) {
            int gcb = bn + wc * 64 + tc * 16 + quad * 4;
            float x[4];
#pragma unroll
            for (int r = 0; r < 4; ++r) {
                float v = acc[tr][tc][r];
                if (EPI >= 1) v += bv[tc][r];
                if (EPI == 2) v = fast_gelu(v);
                x[r] = v;
            }
            uint2 pk;
            pk.x = (unsigned)f2b(x[0]) | ((unsigned)f2b(x[1]) << 16);
            pk.y = (unsigned)f2b(x[2]) | ((unsigned)f2b(x[3]) << 16);
            *(uint2*)(C + (size_t)grow * ldc + gcb) = pk;
        }
    }
}

// MFMA banded attention; PV uses swapped operands (packed 8B output stores).
// LDS XOR chunk-swizzle (r10): Ks/Rs chunk q of row r at (q ^ (r&7));
// VT/Ps chunk q of row r at (q ^ (r&15)). Same on write and read.
// r14: XCD-aware block remap — each XCD owns 4 batches (b = xcd*4 + hi),
// i0 varies fastest, then head, so overlapping K/V windows and per-b qkv
// panels stay resident in the XCD's L2.
__global__ __launch_bounds__(256) void attn_mfma(
    ushort_t* __restrict__ qkv, const ushort_t* __restrict__ krb,
    const void* __restrict__ rwb, const void* __restrict__ rrb, size_t boff,
    const void* __restrict__ im,
    const unsigned int* __restrict__ dtp) {
    const bool isbf = (dtp[0] != FP32_ONE);
    __shared__ ushort_t Ks[128 * 64];
    __shared__ ushort_t VT[64 * 128];
    __shared__ ushort_t Rs[64 * 64];
    __shared__ float    BD2[4 * 16 * 64];
    __shared__ ushort_t Ps[4 * 16 * 128];
    __shared__ float    imk[128];
    __shared__ float    imq[64];

    const int tid = threadIdx.x;
    // XCD remap: bid linear (x fastest). xcd = bid&7; within an XCD slot
    // walks i0 fastest, then head n, then the XCD's 4 batches.
    const int bid  = (blockIdx.z * gridDim.y + blockIdx.y) * gridDim.x + blockIdx.x;
    const int xcd  = bid & 7, slot = bid >> 3;
    const int i0 = (slot & 7) * 64;
    const int n  = (slot >> 3) & 7;
    const int b  = xcd * 4 + (slot >> 6);
    const int o  = OMEGA_C[n];
    const int noff = n * DH;
    const int j0 = i0 - 64;
    const int w = tid >> 6, lane = tid & 63;
    const int quad = lane >> 4, l16 = lane & 15;

#pragma unroll
    for (int it = 0; it < 4; ++it) {
        int q4 = it * 256 + tid;
        int c  = q4 >> 3, ch = q4 & 7;
        int jc = j0 + c; jc = jc < 0 ? 0 : jc;
        size_t rowb = (size_t)(jc * B_ + b) * QKV_LD + noff;
        *(uint4*)(Ks + c * 64 + ((ch ^ (c & 7)) << 3)) = *(const uint4*)(qkv + rowb + 512 + ch * 8);
        ushort_t v8[8];
        *(uint4*)v8 = *(const uint4*)(qkv + rowb + 1024 + ch * 8);
#pragma unroll
        for (int e = 0; e < 8; ++e) {
            int vr = ch * 8 + e;
            VT[vr * 128 + (((c >> 3) ^ (vr & 15)) << 3) + (c & 7)] = v8[e];
        }
    }
#pragma unroll
    for (int it = 0; it < 2; ++it) {
        int q4 = it * 256 + tid;
        int m = q4 >> 3, ch = q4 & 7;
        *(uint4*)(Rs + m * 64 + ((ch ^ (m & 7)) << 3)) =
            *(const uint4*)(krb + (size_t)(512 - m) * 512 + noff + ch * 8);
    }
    if (tid < 128) {
        int j = j0 + tid;
        imk[tid] = (j >= 0) ? ldx(im, b * S_ + j, isbf) : 0.f;
    } else if (tid < 192) {
        imq[tid - 128] = ldx(im, b * S_ + i0 + (tid - 128), isbf);
    }
    __syncthreads();

    const int qrow = i0 + w * 16 + l16;
    size_t qbase = (size_t)(qrow * B_ + b) * QKV_LD + noff;
    short8 aw[2], ar[2];
#pragma unroll
    for (int kc = 0; kc < 2; ++kc) {
        int kof = kc * 32 + quad * 8;
        ushort_t qe[8];
        *(uint4*)qe = *(const uint4*)(qkv + qbase + kof);
#pragma unroll
        for (int e = 0; e < 8; ++e) {
            float f = b2f(qe[e]);
            ((ushort_t*)&aw[kc])[e] = f2b(f + ldx(rwb, boff + noff + kof + e, isbf));
            ((ushort_t*)&ar[kc])[e] = f2b(f + ldx(rrb, boff + noff + kof + e, isbf));
        }
    }

    f32x4 accs[8];
#pragma unroll
    for (int ct = 0; ct < 8; ++ct) {
        int kr = ct * 16 + l16;
        short8 b0 = *(const short8*)(Ks + kr * 64 + ((quad ^ (kr & 7)) << 3));
        short8 b1 = *(const short8*)(Ks + kr * 64 + (((quad + 4) ^ (kr & 7)) << 3));
        f32x4 z = {0.f, 0.f, 0.f, 0.f};
        z = __builtin_amdgcn_mfma_f32_16x16x32_bf16(aw[0], b0, z, 0, 0, 0);
        z = __builtin_amdgcn_mfma_f32_16x16x32_bf16(aw[1], b1, z, 0, 0, 0);
        accs[ct] = z;
    }
    float* BD2w = BD2 + w * 16 * 64;
#pragma unroll
    for (int mt = 0; mt < 4; ++mt) {
        int rr = mt * 16 + l16;
        short8 b0 = *(const short8*)(Rs + rr * 64 + ((quad ^ (rr & 7)) << 3));
        short8 b1 = *(const short8*)(Rs + rr * 64 + (((quad + 4) ^ (rr & 7)) << 3));
        f32x4 z = {0.f, 0.f, 0.f, 0.f};
        z = __builtin_amdgcn_mfma_f32_16x16x32_bf16(ar[0], b0, z, 0, 0, 0);
        z = __builtin_amdgcn_mfma_f32_16x16x32_bf16(ar[1], b1, z, 0, 0, 0);
#pragma unroll
        for (int r = 0; r < 4; ++r)
            BD2w[(quad * 4 + r) * 64 + mt * 16 + l16] = z[r];
    }

    float im_i[4];
#pragma unroll
    for (int r = 0; r < 4; ++r) im_i[r] = imq[w * 16 + quad * 4 + r];

    float sc[8][4];
#pragma unroll
    for (int ct = 0; ct < 8; ++ct) {
        int cl = ct * 16 + l16;
        float imk_c = imk[cl];
#pragma unroll
        for (int r = 0; r < 4; ++r) {
            int qrl = w * 16 + quad * 4 + r;
            int rel = qrl + 64 - cl;
            int relc = rel < 0 ? 0 : (rel > 63 ? 63 : rel);
            float bd = BD2w[(quad * 4 + r) * 64 + relc];
            bool valid = (rel >= 0) && (rel < o) && (rel <= i0 + qrl)
                         && (im_i[r] + imk_c <= 0.f);
            sc[ct][r] = valid ? (accs[ct][r] + bd) * 0.125f : -1e30f;
        }
    }
    float rl[4];
#pragma unroll
    for (int r = 0; r < 4; ++r) {
        float mx = sc[0][r];
#pragma unroll
        for (int ct = 1; ct < 8; ++ct) mx = fmaxf(mx, sc[ct][r]);
        mx = row16_max(mx);
        float l = 0.f;
#pragma unroll
        for (int ct = 0; ct < 8; ++ct) {
            float pv = __expf(sc[ct][r] - mx);
            sc[ct][r] = pv;
            l += pv;
        }
        l = row16_sum(l);
        rl[r] = 1.f / l;
    }
    ushort_t* Pw = Ps + w * 16 * 128;
#pragma unroll
    for (int ct = 0; ct < 8; ++ct)
#pragma unroll
        for (int r = 0; r < 4; ++r) {
            int prow = quad * 4 + r;
            Pw[prow * 128 + ((((ct * 2 + (l16 >> 3)) ^ prow) & 15) << 3) + (l16 & 7)]
                = f2b(sc[ct][r] * rl[r]);
        }

    short8 aP[4];
#pragma unroll
    for (int kc = 0; kc < 4; ++kc)
        aP[kc] = *(const short8*)(Pw + l16 * 128 + ((((kc * 4 + quad) ^ l16) & 15) << 3));

    const int qg = i0 + w * 16 + l16;
    const size_t obase = (size_t)(qg * B_ + b) * QKV_LD + noff;
#pragma unroll
    for (int dt = 0; dt < 4; ++dt) {
        f32x4 accT = {0.f, 0.f, 0.f, 0.f};
#pragma unroll
        for (int kc = 0; kc < 4; ++kc) {
            int vrow = dt * 16 + l16;
            short8 bV = *(const short8*)(VT + vrow * 128 + ((((kc * 4 + quad) ^ (vrow & 15)) & 15) << 3));
            accT = __builtin_amdgcn_mfma_f32_16x16x32_bf16(bV, aP[kc], accT, 0, 0, 0);
        }
        uint2 pk;
        pk.x = (unsigned)f2b(accT[0]) | ((unsigned)f2b(accT[1]) << 16);
        pk.y = (unsigned)f2b(accT[2]) | ((unsigned)f2b(accT[3]) << 16);
        *(uint2*)(qkv + obase + dt * 16 + quad * 4) = pk;
    }
}

// h = LayerNorm(x + h)*w + b. Wave-per-row, uint4, no barriers.
__global__ __launch_bounds__(256) void add_ln_kernel(
    const ushort_t* __restrict__ x, ushort_t* __restrict__ h,
    const void* __restrict__ w, const void* __restrict__ b, size_t boff,
    const unsigned int* __restrict__ dtp) {
    const bool isbf = (dtp[0] != FP32_ONE);
    int lane = threadIdx.x & 63;
    int row = blockIdx.x * 4 + (threadIdx.x >> 6);
    size_t base = (size_t)row * D_ + lane * 8;
    ushort_t xe[8], he[8];
    *(uint4*)xe = *(const uint4*)(x + base);
    *(uint4*)he = *(const uint4*)(h + base);
    float v[8];
    float s = 0.f, ss = 0.f;
#pragma unroll
    for (int e = 0; e < 8; ++e) {
        v[e] = b2f(xe[e]) + b2f(he[e]);
        s += v[e]; ss += v[e] * v[e];
    }
    dpp_sum64(s); dpp_sum64(ss);
    float S = rlane(s, 63), SS = rlane(ss, 63);
    float mu  = S * (1.f / D_);
    float var = fmaxf(SS * (1.f / D_) - mu * mu, 0.f);
    float inv = rsqrtf(var + 1e-8f);
    ushort_t oe[8];
#pragma unroll
    for (int e = 0; e < 8; ++e)
        oe[e] = f2b((v[e] - mu) * inv * ldx(w, boff + lane * 8 + e, isbf)
                    + ldx(b, boff + lane * 8 + e, isbf));
    *(uint4*)(h + base) = *(uint4*)oe;
}

__global__ __launch_bounds__(256) void writeout_kernel(const ushort_t* __restrict__ h,
                                                       void* __restrict__ out,
                                                       const unsigned int* __restrict__ dtp) {
    const bool isbf = (dtp[0] != FP32_ONE);
    int idx = blockIdx.x * 256 + threadIdx.x;        // over M_*D_/8
    int d8 = idx & 63;
    int rest = idx >> 6;                             // b*S + s
    int s = rest & (S_ - 1), b = rest >> 9;
    ushort_t ve[8];
    *(uint4*)ve = *(const uint4*)(h + ((size_t)(s * B_ + b) << 9) + d8 * 8);
    if (isbf) {
        *(uint4*)((ushort_t*)out + (size_t)idx * 8) = *(uint4*)ve;
    } else {
        float* op = (float*)out + (size_t)idx * 8;
        ((float4*)op)[0] = make_float4(b2f(ve[0]), b2f(ve[1]), b2f(ve[2]), b2f(ve[3]));
        ((float4*)op)[1] = make_float4(b2f(ve[4]), b2f(ve[5]), b2f(ve[6]), b2f(ve[7]));
    }
}

extern "C" void kernel_launch(void* const* d_in, const int* in_sizes, int n_in,
                              void* d_out, int out_size, void* d_ws, size_t ws_size,
                              hipStream_t stream) {
    (void)in_sizes; (void)n_in; (void)out_size; (void)ws_size;
    const int*  ids = (const int*)d_in[0];
    const void* im  = d_in[1];
    const void* emb = d_in[2];
    const void* Wq = d_in[3], *Wk = d_in[4], *Wv = d_in[5], *Wr = d_in[6], *Wo = d_in[7];
    const void* rrb = d_in[8], *rwb = d_in[9];
    const void* lnaw = d_in[10], *lnab = d_in[11];
    const void* W1 = d_in[12], *b1 = d_in[13], *W2 = d_in[14], *b2 = d_in[15];
    const void* lnfw = d_in[16], *lnfb = d_in[17];
    const unsigned int* dtp = (const unsigned int*)d_in[10];  // dtype probe

    // ---- workspace layout, ~160 MB ----
    char* wsb = (char*)d_ws;
    ushort_t* h    = (ushort_t*)wsb;                   // [0,16)    bf16 16384x512
    ushort_t* qkv  = (ushort_t*)(wsb + (16u << 20));   // [16,64)   bf16 16384x1536
    ushort_t* tmp  = (ushort_t*)(wsb + (64u << 20));   // [64,80)   bf16 16384x512
    ushort_t* ff1  = (ushort_t*)(wsb + (80u << 20));   // [80,144)  bf16 16384x2048
    ushort_t* wbuf = (ushort_t*)(wsb + (144u << 20));  // [144,157) weights
    ushort_t* posb = (ushort_t*)(wsb + (157u << 20));  // [157,158) bf16 1024x512
    ushort_t* krb0 = (ushort_t*)(wsb + (158u << 20));  // [158,159) bf16 1024x512
    ushort_t* krb1 = (ushort_t*)(wsb + (159u << 20));  // [159,160)

    embed_kernel<<<4096, 256, 0, stream>>>(ids, emb, h, dtp);
    posemb_kernel<<<1024, 256, 0, stream>>>(posb);

    transp_cvt4<<<dim3(16, 16, 8), 256, 0, stream>>>(Wq, Wk, Wv, Wr, wbuf, dtp);
    cvtL<<<dim3(1024, 1, 2), 256, 0, stream>>>(Wo, 262144, wbuf, 1048576, dtp, 262144);
    transp_cvtL<<<dim3(64, 16, 2), 256, 0, stream>>>(W1, 1048576, wbuf, 1310720, dtp, 512, 2048);
    transp_cvtL<<<dim3(16, 64, 2), 256, 0, stream>>>(W2, 1048576, wbuf, 2359296, dtp, 2048, 512);

    // k_r for BOTH layers in one dispatch (z = layer; B stride WL, C stride 512KB)
    mfma_gemm<0><<<dim3(8, 4, 2), 256, 0, stream>>>(posb, 512, wbuf + 786432, 512, nullptr, 0,
                                                    krb0, 512, WL, 524288, dtp, 1024, 512, 512);

    for (int l = 0; l < 2; ++l) {
        size_t boff = (size_t)l * 512;
        size_t b1off = (size_t)l * 2048;
        ushort_t* qkvT = wbuf + (size_t)l * WL;
        ushort_t* woc  = qkvT + 1048576;
        ushort_t* w1T  = woc  + 262144;
        ushort_t* w2T  = w1T  + 1048576;
        ushort_t* krb  = l ? krb1 : krb0;

        // fused q|k|v = h @ [Wq|Wk|Wv] (16384x1536)
        mfma_gemm<0><<<dim3(128, 12), 256, 0, stream>>>(h, 512, qkvT, 512, nullptr, 0, qkv, QKV_LD, 0, 0, dtp, M_, QKV_LD, 512);

        attn_mfma<<<dim3(8, 32, 8), 256, 0, stream>>>(qkv, krb, rwb, rrb, boff, im, dtp);

        // attn_out = av @ Wo^T (av in q slots, lda=1536)
        mfma_gemm<0><<<dim3(128, 4), 256, 0, stream>>>(qkv, QKV_LD, woc, 512, nullptr, 0, tmp, 512, 0, 0, dtp, M_, 512, 512);
        add_ln_kernel<<<4096, 256, 0, stream>>>(tmp, h, lnaw, lnab, boff, dtp);

        // FFN: single FF1 (N=2048) and single FF2 (K=2048)
        mfma_gemm<2><<<dim3(128, 16), 256, 0, stream>>>(h, 512, w1T, 512, b1, b1off, ff1, DI, 0, 0, dtp, M_, DI, 512);
        mfma_gemm<1><<<dim3(128, 4),  256, 0, stream>>>(ff1, DI, w2T, 2048, b2, boff, tmp, 512, 0, 0, dtp, M_, 512, DI);
        add_ln_kernel<<<4096, 256, 0, stream>>>(tmp, h, lnfw, lnfb, boff, dtp);
    }

    writeout_kernel<<<4096, 256, 0, stream>>>(h, d_out, dtp);
}

// Round 6
// 747.557 us; speedup vs baseline: 1.0327x; 1.0115x over previous
//
#include <hip/hip_runtime.h>
#include <math.h>

// DualRec 2-layer transformer-XL model, MI355X — round 15.
// r15 (from r14 counters: GEMMs still MfmaUtil ~17 / VALUBusy ~30 / HBM ~15%
// at 3 blocks/CU — latency-bound, LDS-capped occupancy):
//   mfma_gemm: triple-buffer (48KB, 3 blocks/CU) -> DOUBLE-buffer (32KB,
//   5 blocks/CU) with 1-deep counted-vmcnt prefetch: stage tile t+2 AFTER
//   the closing barrier into the freed buffer; wait vmcnt(4) at step top
//   (tile t forced complete, t+1 stays in flight), vmcnt(0) only on last.
//   Combines r11's occupancy (10 blk single-buf, 70µs) with r12's
//   cross-barrier flight (3 blk tri-buf, 66µs) — takes both levers.
// Carried: r14 krb z=2 merge + attn XCD remap, r11 bn-fastest XCD swizzle +
// A&S erf GELU, r10 attn LDS XOR swizzle + __expf softmax.

#define S_  512
#define B_  32
#define D_  512
#define NH  8
#define DH  64
#define DI  2048
#define M_  (S_*B_)
#define QKV_LD 1536
#define WL  3407872   // per-layer wbuf elements (6.5 MiB)
#define FP32_ONE 0x3F800000u

typedef unsigned short ushort_t;
typedef __attribute__((ext_vector_type(8))) short short8;
typedef __attribute__((ext_vector_type(4))) float f32x4;

__constant__ int OMEGA_C[8] = {2, 3, 4, 5, 7, 11, 21, 50};

__device__ __forceinline__ float b2f(ushort_t us) {
    return __uint_as_float(((unsigned int)us) << 16);
}
__device__ __forceinline__ ushort_t f2b(float f) {
    unsigned int u = __float_as_uint(f);
    return (ushort_t)((u + 0x7fffu + ((u >> 16) & 1u)) >> 16);
}
__device__ __forceinline__ float ldx(const void* p, size_t idx, bool isbf) {
    return isbf ? b2f(((const ushort_t*)p)[idx]) : ((const float*)p)[idx];
}
__device__ __forceinline__ void async16(const ushort_t* g, ushort_t* l) {
    __builtin_amdgcn_global_load_lds(
        (const __attribute__((address_space(1))) unsigned int*)g,
        (__attribute__((address_space(3))) unsigned int*)l, 16, 0, 0);
}

// Branch-free exact-GELU: 0.5*v*(1+erf(v/sqrt2)) via A&S 7.1.26 (|err|<=1.5e-7).
__device__ __forceinline__ float fast_gelu(float v) {
    float x  = v * 0.7071067811865475f;
    float ax = fabsf(x);
    float t  = __builtin_amdgcn_rcpf(fmaf(0.3275911f, ax, 1.f));
    float p  = fmaf(fmaf(fmaf(fmaf(1.061405429f, t, -1.453152027f),
                              t, 1.421413741f),
                         t, -0.284496736f),
                    t, 0.254829592f) * t;
    float e    = __expf(-ax * ax);
    float erfa = fmaf(-p, e, 1.f);          // erf(|x|)
    float erfx = copysignf(erfa, x);
    return 0.5f * v * (1.f + erfx);
}

// ---- DPP reductions ----
#define DPPA(v, ctrl) v += __int_as_float(__builtin_amdgcn_update_dpp(0, __float_as_int(v), ctrl, 0xf, 0xf, true))
__device__ __forceinline__ void dpp_sum64(float& v) {
    DPPA(v, 0x111); DPPA(v, 0x112); DPPA(v, 0x114);
    DPPA(v, 0x118); DPPA(v, 0x142); DPPA(v, 0x143);
}
#define DPPROR(v, ctrl) __int_as_float(__builtin_amdgcn_update_dpp(__float_as_int(v), __float_as_int(v), ctrl, 0xf, 0xf, false))
__device__ __forceinline__ float row16_sum(float v) {
    v += DPPROR(v, 0x128); v += DPPROR(v, 0x124);
    v += DPPROR(v, 0x122); v += DPPROR(v, 0x121);
    return v;
}
__device__ __forceinline__ float row16_max(float v) {
    v = fmaxf(v, DPPROR(v, 0x128)); v = fmaxf(v, DPPROR(v, 0x124));
    v = fmaxf(v, DPPROR(v, 0x122)); v = fmaxf(v, DPPROR(v, 0x121));
    return v;
}
__device__ __forceinline__ float rlane(float v, int l) {
    return __int_as_float(__builtin_amdgcn_readlane(__float_as_int(v), l));
}

__global__ __launch_bounds__(256) void embed_kernel(const int* __restrict__ ids,
                                                    const void* __restrict__ emb,
                                                    ushort_t* __restrict__ h,
                                                    const unsigned int* __restrict__ dtp) {
    const bool isbf = (dtp[0] != FP32_ONE);
    int idx = blockIdx.x * 256 + threadIdx.x;        // over M_*D_/8
    int d8 = idx & 63;
    int row = idx >> 6;                              // i*B + b
    int s = row >> 5, b = row & 31;
    int id = ids[b * S_ + s];
    size_t src = (size_t)id * D_ + d8 * 8;
    if (isbf) {
        *(uint4*)(h + (size_t)row * D_ + d8 * 8) = *(const uint4*)((const ushort_t*)emb + src);
    } else {
        const float* e = (const float*)emb + src;
        float4 a0 = ((const float4*)e)[0], a1 = ((const float4*)e)[1];
        uint4 pk;
        pk.x = (unsigned)f2b(a0.x) | ((unsigned)f2b(a0.y) << 16);
        pk.y = (unsigned)f2b(a0.z) | ((unsigned)f2b(a0.w) << 16);
        pk.z = (unsigned)f2b(a1.x) | ((unsigned)f2b(a1.y) << 16);
        pk.w = (unsigned)f2b(a1.z) | ((unsigned)f2b(a1.w) << 16);
        *(uint4*)(h + (size_t)row * D_ + d8 * 8) = pk;
    }
}

__global__ __launch_bounds__(256) void posemb_kernel(ushort_t* __restrict__ pos) {
    int flat = blockIdx.x * 256 + threadIdx.x;       // over 1024*256
    int p = flat >> 8, k = flat & 255;
    float inv = expf((float)k * -0.035977892078031f);
    float val = (512.0f - (float)p) * inv;
    pos[p * D_ + k]       = f2b(sinf(val));
    pos[p * D_ + 256 + k] = f2b(cosf(val));
}

__global__ __launch_bounds__(256) void transp_cvt4(
    const void* __restrict__ s0, const void* __restrict__ s1,
    const void* __restrict__ s2, const void* __restrict__ s3,
    ushort_t* __restrict__ wbuf, const unsigned int* __restrict__ dtp) {
    const bool isbf = (dtp[0] != FP32_ONE);
    __shared__ float tt[32][33];
    int z = blockIdx.z, layer = z >> 2, t4 = z & 3;
    const void* srcs[4] = {s0, s1, s2, s3};
    const void* in = srcs[t4];
    size_t inoff = (size_t)layer * 262144;
    ushort_t* out = wbuf + (size_t)layer * WL + (size_t)t4 * 262144;
    int tx = threadIdx.x & 31, ty = threadIdx.x >> 5;
    int n0 = blockIdx.x * 32, k0 = blockIdx.y * 32;
#pragma unroll
    for (int it = 0; it < 4; ++it)
        tt[ty + it * 8][tx] = ldx(in, inoff + (size_t)(k0 + ty + it * 8) * 512 + n0 + tx, isbf);
    __syncthreads();
#pragma unroll
    for (int it = 0; it < 4; ++it)
        out[(size_t)(n0 + ty + it * 8) * 512 + k0 + tx] = f2b(tt[tx][ty + it * 8]);
}

__global__ __launch_bounds__(256) void transp_cvtL(const void* __restrict__ in, size_t perlin,
                                                   ushort_t* __restrict__ wbuf, size_t outoff,
                                                   const unsigned int* __restrict__ dtp,
                                                   int K, int N) {
    const bool isbf = (dtp[0] != FP32_ONE);
    __shared__ float tt[32][33];
    int layer = blockIdx.z;
    size_t inoff = (size_t)layer * perlin;
    ushort_t* out = wbuf + (size_t)layer * WL + outoff;
    int tx = threadIdx.x & 31, ty = threadIdx.x >> 5;
    int n0 = blockIdx.x * 32, k0 = blockIdx.y * 32;
#pragma unroll
    for (int it = 0; it < 4; ++it)
        tt[ty + it * 8][tx] = ldx(in, inoff + (size_t)(k0 + ty + it * 8) * N + n0 + tx, isbf);
    __syncthreads();
#pragma unroll
    for (int it = 0; it < 4; ++it)
        out[(size_t)(n0 + ty + it * 8) * K + k0 + tx] = f2b(tt[tx][ty + it * 8]);
}

__global__ __launch_bounds__(256) void cvtL(const void* __restrict__ in, size_t perlin,
                                            ushort_t* __restrict__ wbuf, size_t outoff,
                                            const unsigned int* __restrict__ dtp, int nelem) {
    const bool isbf = (dtp[0] != FP32_ONE);
    int layer = blockIdx.z;
    int i = blockIdx.x * 256 + threadIdx.x;
    if (i < nelem)
        wbuf[(size_t)layer * WL + outoff + i] = f2b(ldx(in, (size_t)layer * perlin + i, isbf));
}

// C[M,N] = A[M,K](bf16, lda) x B^T[n][k](bf16, ldb).
// EPI: 0 none, 1 +bias, 2 +bias+exact GELU. Swapped-operand MFMA: lane owns
// C[row l16][4 consecutive cols] -> 8B packed bf16 stores.
// r15: DOUBLE-buffered counted-vmcnt K-loop — 32KB LDS -> 5 blocks/CU.
// Stage tile t+2 after the closing barrier (buffer just freed); top-of-step
// wait vmcnt(4) keeps tile t+1's 4 loads in flight across both barriers.
template<int EPI>
__global__ __launch_bounds__(256)
void mfma_gemm(const ushort_t* __restrict__ A, int lda,
               const ushort_t* __restrict__ Bt, int ldb,
               const void* __restrict__ biasv, size_t biasoff,
               ushort_t* __restrict__ C, int ldc,
               size_t bzoff, size_t czoff,
               const unsigned int* __restrict__ dtp, int M, int N, int K) {
    const bool isbf = (dtp[0] != FP32_ONE);
    __shared__ ushort_t As[2][128 * 32];
    __shared__ ushort_t Bs[2][128 * 32];
    const int tid = threadIdx.x;
    Bt += (size_t)blockIdx.z * bzoff;
    C  += (size_t)blockIdx.z * czoff;
    // XCD swizzle (nwg % 8 == 0 at all call sites): contiguous swz chunk per
    // XCD; within the chunk bn varies fastest (B panel L2-resident).
    const int nwg = gridDim.x * gridDim.y;
    const int wg  = blockIdx.y * gridDim.x + blockIdx.x;
    const int cpx = nwg >> 3;
    const int swz = (wg & 7) * cpx + (wg >> 3);
    const int bm = (swz / gridDim.y) * 128;
    const int bn = (swz % gridDim.y) * 128;
    const int w = tid >> 6, lane = tid & 63;
    const int wr = w >> 1, wc = w & 1;
    const int quad = lane >> 4, l16 = lane & 15;
    const int rsub = lane >> 2;
    const int kcg  = (lane & 3) ^ ((rsub >> 1) & 3);
    const int fsw  = (l16 >> 1) & 3;

    const ushort_t* ga0 = A  + (size_t)(bm + w * 16 + rsub) * lda + kcg * 8;
    const ushort_t* ga1 = A  + (size_t)(bm + (4 + w) * 16 + rsub) * lda + kcg * 8;
    const ushort_t* gb0 = Bt + (size_t)(bn + w * 16 + rsub) * ldb + kcg * 8;
    const ushort_t* gb1 = Bt + (size_t)(bn + (4 + w) * 16 + rsub) * ldb + kcg * 8;

#define STAGE_T(kt, bi) do {                                  \
        int _k0 = (kt) << 5;                                  \
        async16(ga0 + _k0, As[bi] + w * 512);                 \
        async16(gb0 + _k0, Bs[bi] + w * 512);                 \
        async16(ga1 + _k0, As[bi] + (4 + w) * 512);           \
        async16(gb1 + _k0, Bs[bi] + (4 + w) * 512);           \
    } while (0)

    f32x4 acc[4][4];
#pragma unroll
    for (int i = 0; i < 4; ++i)
#pragma unroll
        for (int j = 0; j < 4; ++j)
#pragma unroll
            for (int r = 0; r < 4; ++r) acc[i][j][r] = 0.f;

    const int nt = K >> 5;      // >= 16 at all call sites
    STAGE_T(0, 0);
    STAGE_T(1, 1);
    for (int t = 0; t < nt; ++t) {
        const int cur = t & 1;
        // tile t forced complete; tile t+1 (4 loads) stays in flight.
        if (t + 1 < nt) asm volatile("s_waitcnt vmcnt(4)" ::: "memory");
        else            asm volatile("s_waitcnt vmcnt(0)" ::: "memory");
        __builtin_amdgcn_s_barrier();
        asm volatile("" ::: "memory");   // keep LDS reads below the barrier

        short8 af[4], bf[4];
#pragma unroll
        for (int tt = 0; tt < 4; ++tt) {
            int ra = wr * 64 + tt * 16 + l16;
            int rb = wc * 64 + tt * 16 + l16;
            af[tt] = *(const short8*)(As[cur] + ra * 32 + ((quad ^ fsw) * 8));
            bf[tt] = *(const short8*)(Bs[cur] + rb * 32 + ((quad ^ fsw) * 8));
        }
#pragma unroll
        for (int tr = 0; tr < 4; ++tr)
#pragma unroll
            for (int tc = 0; tc < 4; ++tc)
                acc[tr][tc] = __builtin_amdgcn_mfma_f32_16x16x32_bf16(bf[tc], af[tr], acc[tr][tc], 0, 0, 0);

        asm volatile("s_waitcnt lgkmcnt(0)" ::: "memory");  // reads done before overwrite
        __builtin_amdgcn_s_barrier();
        if (t + 2 < nt) STAGE_T(t + 2, cur);   // refill the buffer just freed
    }
#undef STAGE_T

    float bv[4][4];
    if (EPI >= 1) {
#pragma unroll
        for (int tc = 0; tc < 4; ++tc)
#pragma unroll
            for (int r = 0; r < 4; ++r)
                bv[tc][r] = ldx(biasv, biasoff + bn + wc * 64 + tc * 16 + quad * 4 + r, isbf);
    }
#pragma unroll
    for (int tr = 0; tr < 4; ++tr) {
        int grow = bm + wr * 64 + tr * 16 + l16;
#pragma unroll
        for (int tc = 0; tc < 4; ++tc) {
            int gcb = bn + wc * 64 + tc * 16 + quad * 4;
            float x[4];
#pragma unroll
            for (int r = 0; r < 4; ++r) {
                float v = acc[tr][tc][r];
                if (EPI >= 1) v += bv[tc][r];
                if (EPI == 2) v = fast_gelu(v);
                x[r] = v;
            }
            uint2 pk;
            pk.x = (unsigned)f2b(x[0]) | ((unsigned)f2b(x[1]) << 16);
            pk.y = (unsigned)f2b(x[2]) | ((unsigned)f2b(x[3]) << 16);
            *(uint2*)(C + (size_t)grow * ldc + gcb) = pk;
        }
    }
}

// MFMA banded attention; PV uses swapped operands (packed 8B output stores).
// LDS XOR chunk-swizzle (r10): Ks/Rs chunk q of row r at (q ^ (r&7));
// VT/Ps chunk q of row r at (q ^ (r&15)). Same on write and read.
// XCD-aware block remap (r14): each XCD owns 4 batches, i0 fastest.
__global__ __launch_bounds__(256) void attn_mfma(
    ushort_t* __restrict__ qkv, const ushort_t* __restrict__ krb,
    const void* __restrict__ rwb, const void* __restrict__ rrb, size_t boff,
    const void* __restrict__ im,
    const unsigned int* __restrict__ dtp) {
    const bool isbf = (dtp[0] != FP32_ONE);
    __shared__ ushort_t Ks[128 * 64];
    __shared__ ushort_t VT[64 * 128];
    __shared__ ushort_t Rs[64 * 64];
    __shared__ float    BD2[4 * 16 * 64];
    __shared__ ushort_t Ps[4 * 16 * 128];
    __shared__ float    imk[128];
    __shared__ float    imq[64];

    const int tid = threadIdx.x;
    const int bid  = (blockIdx.z * gridDim.y + blockIdx.y) * gridDim.x + blockIdx.x;
    const int xcd  = bid & 7, slot = bid >> 3;
    const int i0 = (slot & 7) * 64;
    const int n  = (slot >> 3) & 7;
    const int b  = xcd * 4 + (slot >> 6);
    const int o  = OMEGA_C[n];
    const int noff = n * DH;
    const int j0 = i0 - 64;
    const int w = tid >> 6, lane = tid & 63;
    const int quad = lane >> 4, l16 = lane & 15;

#pragma unroll
    for (int it = 0; it < 4; ++it) {
        int q4 = it * 256 + tid;
        int c  = q4 >> 3, ch = q4 & 7;
        int jc = j0 + c; jc = jc < 0 ? 0 : jc;
        size_t rowb = (size_t)(jc * B_ + b) * QKV_LD + noff;
        *(uint4*)(Ks + c * 64 + ((ch ^ (c & 7)) << 3)) = *(const uint4*)(qkv + rowb + 512 + ch * 8);
        ushort_t v8[8];
        *(uint4*)v8 = *(const uint4*)(qkv + rowb + 1024 + ch * 8);
#pragma unroll
        for (int e = 0; e < 8; ++e) {
            int vr = ch * 8 + e;
            VT[vr * 128 + (((c >> 3) ^ (vr & 15)) << 3) + (c & 7)] = v8[e];
        }
    }
#pragma unroll
    for (int it = 0; it < 2; ++it) {
        int q4 = it * 256 + tid;
        int m = q4 >> 3, ch = q4 & 7;
        *(uint4*)(Rs + m * 64 + ((ch ^ (m & 7)) << 3)) =
            *(const uint4*)(krb + (size_t)(512 - m) * 512 + noff + ch * 8);
    }
    if (tid < 128) {
        int j = j0 + tid;
        imk[tid] = (j >= 0) ? ldx(im, b * S_ + j, isbf) : 0.f;
    } else if (tid < 192) {
        imq[tid - 128] = ldx(im, b * S_ + i0 + (tid - 128), isbf);
    }
    __syncthreads();

    const int qrow = i0 + w * 16 + l16;
    size_t qbase = (size_t)(qrow * B_ + b) * QKV_LD + noff;
    short8 aw[2], ar[2];
#pragma unroll
    for (int kc = 0; kc < 2; ++kc) {
        int kof = kc * 32 + quad * 8;
        ushort_t qe[8];
        *(uint4*)qe = *(const uint4*)(qkv + qbase + kof);
#pragma unroll
        for (int e = 0; e < 8; ++e) {
            float f = b2f(qe[e]);
            ((ushort_t*)&aw[kc])[e] = f2b(f + ldx(rwb, boff + noff + kof + e, isbf));
            ((ushort_t*)&ar[kc])[e] = f2b(f + ldx(rrb, boff + noff + kof + e, isbf));
        }
    }

    f32x4 accs[8];
#pragma unroll
    for (int ct = 0; ct < 8; ++ct) {
        int kr = ct * 16 + l16;
        short8 b0 = *(const short8*)(Ks + kr * 64 + ((quad ^ (kr & 7)) << 3));
        short8 b1 = *(const short8*)(Ks + kr * 64 + (((quad + 4) ^ (kr & 7)) << 3));
        f32x4 z = {0.f, 0.f, 0.f, 0.f};
        z = __builtin_amdgcn_mfma_f32_16x16x32_bf16(aw[0], b0, z, 0, 0, 0);
        z = __builtin_amdgcn_mfma_f32_16x16x32_bf16(aw[1], b1, z, 0, 0, 0);
        accs[ct] = z;
    }
    float* BD2w = BD2 + w * 16 * 64;
#pragma unroll
    for (int mt = 0; mt < 4; ++mt) {
        int rr = mt * 16 + l16;
        short8 b0 = *(const short8*)(Rs + rr * 64 + ((quad ^ (rr & 7)) << 3));
        short8 b1 = *(const short8*)(Rs + rr * 64 + (((quad + 4) ^ (rr & 7)) << 3));
        f32x4 z = {0.f, 0.f, 0.f, 0.f};
        z = __builtin_amdgcn_mfma_f32_16x16x32_bf16(ar[0], b0, z, 0, 0, 0);
        z = __builtin_amdgcn_mfma_f32_16x16x32_bf16(ar[1], b1, z, 0, 0, 0);
#pragma unroll
        for (int r = 0; r < 4; ++r)
            BD2w[(quad * 4 + r) * 64 + mt * 16 + l16] = z[r];
    }

    float im_i[4];
#pragma unroll
    for (int r = 0; r < 4; ++r) im_i[r] = imq[w * 16 + quad * 4 + r];

    float sc[8][4];
#pragma unroll
    for (int ct = 0; ct < 8; ++ct) {
        int cl = ct * 16 + l16;
        float imk_c = imk[cl];
#pragma unroll
        for (int r = 0; r < 4; ++r) {
            int qrl = w * 16 + quad * 4 + r;
            int rel = qrl + 64 - cl;
            int relc = rel < 0 ? 0 : (rel > 63 ? 63 : rel);
            float bd = BD2w[(quad * 4 + r) * 64 + relc];
            bool valid = (rel >= 0) && (rel < o) && (rel <= i0 + qrl)
                         && (im_i[r] + imk_c <= 0.f);
            sc[ct][r] = valid ? (accs[ct][r] + bd) * 0.125f : -1e30f;
        }
    }
    float rl[4];
#pragma unroll
    for (int r = 0; r < 4; ++r) {
        float mx = sc[0][r];
#pragma unroll
        for (int ct = 1; ct < 8; ++ct) mx = fmaxf(mx, sc[ct][r]);
        mx = row16_max(mx);
        float l = 0.f;
#pragma unroll
        for (int ct = 0; ct < 8; ++ct) {
            float pv = __expf(sc[ct][r] - mx);
            sc[ct][r] = pv;
            l += pv;
        }
        l = row16_sum(l);
        rl[r] = 1.f / l;
    }
    ushort_t* Pw = Ps + w * 16 * 128;
#pragma unroll
    for (int ct = 0; ct < 8; ++ct)
#pragma unroll
        for (int r = 0; r < 4; ++r) {
            int prow = quad * 4 + r;
            Pw[prow * 128 + ((((ct * 2 + (l16 >> 3)) ^ prow) & 15) << 3) + (l16 & 7)]
                = f2b(sc[ct][r] * rl[r]);
        }

    short8 aP[4];
#pragma unroll
    for (int kc = 0; kc < 4; ++kc)
        aP[kc] = *(const short8*)(Pw + l16 * 128 + ((((kc * 4 + quad) ^ l16) & 15) << 3));

    const int qg = i0 + w * 16 + l16;
    const size_t obase = (size_t)(qg * B_ + b) * QKV_LD + noff;
#pragma unroll
    for (int dt = 0; dt < 4; ++dt) {
        f32x4 accT = {0.f, 0.f, 0.f, 0.f};
#pragma unroll
        for (int kc = 0; kc < 4; ++kc) {
            int vrow = dt * 16 + l16;
            short8 bV = *(const short8*)(VT + vrow * 128 + ((((kc * 4 + quad) ^ (vrow & 15)) & 15) << 3));
            accT = __builtin_amdgcn_mfma_f32_16x16x32_bf16(bV, aP[kc], accT, 0, 0, 0);
        }
        uint2 pk;
        pk.x = (unsigned)f2b(accT[0]) | ((unsigned)f2b(accT[1]) << 16);
        pk.y = (unsigned)f2b(accT[2]) | ((unsigned)f2b(accT[3]) << 16);
        *(uint2*)(qkv + obase + dt * 16 + quad * 4) = pk;
    }
}

// h = LayerNorm(x + h)*w + b. Wave-per-row, uint4, no barriers.
__global__ __launch_bounds__(256) void add_ln_kernel(
    const ushort_t* __restrict__ x, ushort_t* __restrict__ h,
    const void* __restrict__ w, const void* __restrict__ b, size_t boff,
    const unsigned int* __restrict__ dtp) {
    const bool isbf = (dtp[0] != FP32_ONE);
    int lane = threadIdx.x & 63;
    int row = blockIdx.x * 4 + (threadIdx.x >> 6);
    size_t base = (size_t)row * D_ + lane * 8;
    ushort_t xe[8], he[8];
    *(uint4*)xe = *(const uint4*)(x + base);
    *(uint4*)he = *(const uint4*)(h + base);
    float v[8];
    float s = 0.f, ss = 0.f;
#pragma unroll
    for (int e = 0; e < 8; ++e) {
        v[e] = b2f(xe[e]) + b2f(he[e]);
        s += v[e]; ss += v[e] * v[e];
    }
    dpp_sum64(s); dpp_sum64(ss);
    float S = rlane(s, 63), SS = rlane(ss, 63);
    float mu  = S * (1.f / D_);
    float var = fmaxf(SS * (1.f / D_) - mu * mu, 0.f);
    float inv = rsqrtf(var + 1e-8f);
    ushort_t oe[8];
#pragma unroll
    for (int e = 0; e < 8; ++e)
        oe[e] = f2b((v[e] - mu) * inv * ldx(w, boff + lane * 8 + e, isbf)
                    + ldx(b, boff + lane * 8 + e, isbf));
    *(uint4*)(h + base) = *(uint4*)oe;
}

__global__ __launch_bounds__(256) void writeout_kernel(const ushort_t* __restrict__ h,
                                                       void* __restrict__ out,
                                                       const unsigned int* __restrict__ dtp) {
    const bool isbf = (dtp[0] != FP32_ONE);
    int idx = blockIdx.x * 256 + threadIdx.x;        // over M_*D_/8
    int d8 = idx & 63;
    int rest = idx >> 6;                             // b*S + s
    int s = rest & (S_ - 1), b = rest >> 9;
    ushort_t ve[8];
    *(uint4*)ve = *(const uint4*)(h + ((size_t)(s * B_ + b) << 9) + d8 * 8);
    if (isbf) {
        *(uint4*)((ushort_t*)out + (size_t)idx * 8) = *(uint4*)ve;
    } else {
        float* op = (float*)out + (size_t)idx * 8;
        ((float4*)op)[0] = make_float4(b2f(ve[0]), b2f(ve[1]), b2f(ve[2]), b2f(ve[3]));
        ((float4*)op)[1] = make_float4(b2f(ve[4]), b2f(ve[5]), b2f(ve[6]), b2f(ve[7]));
    }
}

extern "C" void kernel_launch(void* const* d_in, const int* in_sizes, int n_in,
                              void* d_out, int out_size, void* d_ws, size_t ws_size,
                              hipStream_t stream) {
    (void)in_sizes; (void)n_in; (void)out_size; (void)ws_size;
    const int*  ids = (const int*)d_in[0];
    const void* im  = d_in[1];
    const void* emb = d_in[2];
    const void* Wq = d_in[3], *Wk = d_in[4], *Wv = d_in[5], *Wr = d_in[6], *Wo = d_in[7];
    const void* rrb = d_in[8], *rwb = d_in[9];
    const void* lnaw = d_in[10], *lnab = d_in[11];
    const void* W1 = d_in[12], *b1 = d_in[13], *W2 = d_in[14], *b2 = d_in[15];
    const void* lnfw = d_in[16], *lnfb = d_in[17];
    const unsigned int* dtp = (const unsigned int*)d_in[10];  // dtype probe

    // ---- workspace layout, ~160 MB ----
    char* wsb = (char*)d_ws;
    ushort_t* h    = (ushort_t*)wsb;                   // [0,16)    bf16 16384x512
    ushort_t* qkv  = (ushort_t*)(wsb + (16u << 20));   // [16,64)   bf16 16384x1536
    ushort_t* tmp  = (ushort_t*)(wsb + (64u << 20));   // [64,80)   bf16 16384x512
    ushort_t* ff1  = (ushort_t*)(wsb + (80u << 20));   // [80,144)  bf16 16384x2048
    ushort_t* wbuf = (ushort_t*)(wsb + (144u << 20));  // [144,157) weights
    ushort_t* posb = (ushort_t*)(wsb + (157u << 20));  // [157,158) bf16 1024x512
    ushort_t* krb0 = (ushort_t*)(wsb + (158u << 20));  // [158,159) bf16 1024x512
    ushort_t* krb1 = (ushort_t*)(wsb + (159u << 20));  // [159,160)

    embed_kernel<<<4096, 256, 0, stream>>>(ids, emb, h, dtp);
    posemb_kernel<<<1024, 256, 0, stream>>>(posb);

    transp_cvt4<<<dim3(16, 16, 8), 256, 0, stream>>>(Wq, Wk, Wv, Wr, wbuf, dtp);
    cvtL<<<dim3(1024, 1, 2), 256, 0, stream>>>(Wo, 262144, wbuf, 1048576, dtp, 262144);
    transp_cvtL<<<dim3(64, 16, 2), 256, 0, stream>>>(W1, 1048576, wbuf, 1310720, dtp, 512, 2048);
    transp_cvtL<<<dim3(16, 64, 2), 256, 0, stream>>>(W2, 1048576, wbuf, 2359296, dtp, 2048, 512);

    // k_r for BOTH layers in one dispatch (z = layer; B stride WL, C stride 512KB)
    mfma_gemm<0><<<dim3(8, 4, 2), 256, 0, stream>>>(posb, 512, wbuf + 786432, 512, nullptr, 0,
                                                    krb0, 512, WL, 524288, dtp, 1024, 512, 512);

    for (int l = 0; l < 2; ++l) {
        size_t boff = (size_t)l * 512;
        size_t b1off = (size_t)l * 2048;
        ushort_t* qkvT = wbuf + (size_t)l * WL;
        ushort_t* woc  = qkvT + 1048576;
        ushort_t* w1T  = woc  + 262144;
        ushort_t* w2T  = w1T  + 1048576;
        ushort_t* krb  = l ? krb1 : krb0;

        // fused q|k|v = h @ [Wq|Wk|Wv] (16384x1536)
        mfma_gemm<0><<<dim3(128, 12), 256, 0, stream>>>(h, 512, qkvT, 512, nullptr, 0, qkv, QKV_LD, 0, 0, dtp, M_, QKV_LD, 512);

        attn_mfma<<<dim3(8, 32, 8), 256, 0, stream>>>(qkv, krb, rwb, rrb, boff, im, dtp);

        // attn_out = av @ Wo^T (av in q slots, lda=1536)
        mfma_gemm<0><<<dim3(128, 4), 256, 0, stream>>>(qkv, QKV_LD, woc, 512, nullptr, 0, tmp, 512, 0, 0, dtp, M_, 512, 512);
        add_ln_kernel<<<4096, 256, 0, stream>>>(tmp, h, lnaw, lnab, boff, dtp);

        // FFN: single FF1 (N=2048) and single FF2 (K=2048)
        mfma_gemm<2><<<dim3(128, 16), 256, 0, stream>>>(h, 512, w1T, 512, b1, b1off, ff1, DI, 0, 0, dtp, M_, DI, 512);
        mfma_gemm<1><<<dim3(128, 4),  256, 0, stream>>>(ff1, DI, w2T, 2048, b2, boff, tmp, 512, 0, 0, dtp, M_, 512, DI);
        add_ln_kernel<<<4096, 256, 0, stream>>>(tmp, h, lnfw, lnfb, boff, dtp);
    }

    writeout_kernel<<<4096, 256, 0, stream>>>(h, d_out, dtp);
}

// Round 7
// 726.779 us; speedup vs baseline: 1.0623x; 1.0286x over previous
//
#include <hip/hip_runtime.h>
#include <math.h>

// DualRec 2-layer transformer-XL model, MI355X — round 16.
// r16 (from r11/r12/r15 counters: occupancy PINNED at ~26% across LDS
// 16/48/32KB -> limiter is REGISTERS, not LDS: 84 arch VGPR + 64 AGPR acc
// = 3 waves/SIMD):
//   mfma_gemm rebuilt at 512 threads / 8 waves, same 128x128x32 tile.
//   Wave tile 64x32 -> acc[4][2] (32 AGPR) + af[4]+bf[2] -> ~75 VGPR/wave
//   -> 6+ waves/SIMD; 8-wave blocks x 4 blocks/CU = 32 waves/CU (occ cap).
//   Staging: each thread 1 A + 1 B async16 per tile (2/thread); counted
//   vmcnt(2) keeps next tile in flight; vmcnt(0) only on last. Same XOR
//   chunk swizzle, same double-buffer (32KB), same epilogues.
// Carried: r14 krb z=2 merge + attn XCD remap, r11 bn-fastest XCD swizzle +
// A&S erf GELU, r10 attn LDS XOR swizzle + __expf softmax.

#define S_  512
#define B_  32
#define D_  512
#define NH  8
#define DH  64
#define DI  2048
#define M_  (S_*B_)
#define QKV_LD 1536
#define WL  3407872   // per-layer wbuf elements (6.5 MiB)
#define FP32_ONE 0x3F800000u

typedef unsigned short ushort_t;
typedef __attribute__((ext_vector_type(8))) short short8;
typedef __attribute__((ext_vector_type(4))) float f32x4;

__constant__ int OMEGA_C[8] = {2, 3, 4, 5, 7, 11, 21, 50};

__device__ __forceinline__ float b2f(ushort_t us) {
    return __uint_as_float(((unsigned int)us) << 16);
}
__device__ __forceinline__ ushort_t f2b(float f) {
    unsigned int u = __float_as_uint(f);
    return (ushort_t)((u + 0x7fffu + ((u >> 16) & 1u)) >> 16);
}
__device__ __forceinline__ float ldx(const void* p, size_t idx, bool isbf) {
    return isbf ? b2f(((const ushort_t*)p)[idx]) : ((const float*)p)[idx];
}
__device__ __forceinline__ void async16(const ushort_t* g, ushort_t* l) {
    __builtin_amdgcn_global_load_lds(
        (const __attribute__((address_space(1))) unsigned int*)g,
        (__attribute__((address_space(3))) unsigned int*)l, 16, 0, 0);
}

// Branch-free exact-GELU: 0.5*v*(1+erf(v/sqrt2)) via A&S 7.1.26 (|err|<=1.5e-7).
__device__ __forceinline__ float fast_gelu(float v) {
    float x  = v * 0.7071067811865475f;
    float ax = fabsf(x);
    float t  = __builtin_amdgcn_rcpf(fmaf(0.3275911f, ax, 1.f));
    float p  = fmaf(fmaf(fmaf(fmaf(1.061405429f, t, -1.453152027f),
                              t, 1.421413741f),
                         t, -0.284496736f),
                    t, 0.254829592f) * t;
    float e    = __expf(-ax * ax);
    float erfa = fmaf(-p, e, 1.f);          // erf(|x|)
    float erfx = copysignf(erfa, x);
    return 0.5f * v * (1.f + erfx);
}

// ---- DPP reductions ----
#define DPPA(v, ctrl) v += __int_as_float(__builtin_amdgcn_update_dpp(0, __float_as_int(v), ctrl, 0xf, 0xf, true))
__device__ __forceinline__ void dpp_sum64(float& v) {
    DPPA(v, 0x111); DPPA(v, 0x112); DPPA(v, 0x114);
    DPPA(v, 0x118); DPPA(v, 0x142); DPPA(v, 0x143);
}
#define DPPROR(v, ctrl) __int_as_float(__builtin_amdgcn_update_dpp(__float_as_int(v), __float_as_int(v), ctrl, 0xf, 0xf, false))
__device__ __forceinline__ float row16_sum(float v) {
    v += DPPROR(v, 0x128); v += DPPROR(v, 0x124);
    v += DPPROR(v, 0x122); v += DPPROR(v, 0x121);
    return v;
}
__device__ __forceinline__ float row16_max(float v) {
    v = fmaxf(v, DPPROR(v, 0x128)); v = fmaxf(v, DPPROR(v, 0x124));
    v = fmaxf(v, DPPROR(v, 0x122)); v = fmaxf(v, DPPROR(v, 0x121));
    return v;
}
__device__ __forceinline__ float rlane(float v, int l) {
    return __int_as_float(__builtin_amdgcn_readlane(__float_as_int(v), l));
}

__global__ __launch_bounds__(256) void embed_kernel(const int* __restrict__ ids,
                                                    const void* __restrict__ emb,
                                                    ushort_t* __restrict__ h,
                                                    const unsigned int* __restrict__ dtp) {
    const bool isbf = (dtp[0] != FP32_ONE);
    int idx = blockIdx.x * 256 + threadIdx.x;        // over M_*D_/8
    int d8 = idx & 63;
    int row = idx >> 6;                              // i*B + b
    int s = row >> 5, b = row & 31;
    int id = ids[b * S_ + s];
    size_t src = (size_t)id * D_ + d8 * 8;
    if (isbf) {
        *(uint4*)(h + (size_t)row * D_ + d8 * 8) = *(const uint4*)((const ushort_t*)emb + src);
    } else {
        const float* e = (const float*)emb + src;
        float4 a0 = ((const float4*)e)[0], a1 = ((const float4*)e)[1];
        uint4 pk;
        pk.x = (unsigned)f2b(a0.x) | ((unsigned)f2b(a0.y) << 16);
        pk.y = (unsigned)f2b(a0.z) | ((unsigned)f2b(a0.w) << 16);
        pk.z = (unsigned)f2b(a1.x) | ((unsigned)f2b(a1.y) << 16);
        pk.w = (unsigned)f2b(a1.z) | ((unsigned)f2b(a1.w) << 16);
        *(uint4*)(h + (size_t)row * D_ + d8 * 8) = pk;
    }
}

__global__ __launch_bounds__(256) void posemb_kernel(ushort_t* __restrict__ pos) {
    int flat = blockIdx.x * 256 + threadIdx.x;       // over 1024*256
    int p = flat >> 8, k = flat & 255;
    float inv = expf((float)k * -0.035977892078031f);
    float val = (512.0f - (float)p) * inv;
    pos[p * D_ + k]       = f2b(sinf(val));
    pos[p * D_ + 256 + k] = f2b(cosf(val));
}

__global__ __launch_bounds__(256) void transp_cvt4(
    const void* __restrict__ s0, const void* __restrict__ s1,
    const void* __restrict__ s2, const void* __restrict__ s3,
    ushort_t* __restrict__ wbuf, const unsigned int* __restrict__ dtp) {
    const bool isbf = (dtp[0] != FP32_ONE);
    __shared__ float tt[32][33];
    int z = blockIdx.z, layer = z >> 2, t4 = z & 3;
    const void* srcs[4] = {s0, s1, s2, s3};
    const void* in = srcs[t4];
    size_t inoff = (size_t)layer * 262144;
    ushort_t* out = wbuf + (size_t)layer * WL + (size_t)t4 * 262144;
    int tx = threadIdx.x & 31, ty = threadIdx.x >> 5;
    int n0 = blockIdx.x * 32, k0 = blockIdx.y * 32;
#pragma unroll
    for (int it = 0; it < 4; ++it)
        tt[ty + it * 8][tx] = ldx(in, inoff + (size_t)(k0 + ty + it * 8) * 512 + n0 + tx, isbf);
    __syncthreads();
#pragma unroll
    for (int it = 0; it < 4; ++it)
        out[(size_t)(n0 + ty + it * 8) * 512 + k0 + tx] = f2b(tt[tx][ty + it * 8]);
}

__global__ __launch_bounds__(256) void transp_cvtL(const void* __restrict__ in, size_t perlin,
                                                   ushort_t* __restrict__ wbuf, size_t outoff,
                                                   const unsigned int* __restrict__ dtp,
                                                   int K, int N) {
    const bool isbf = (dtp[0] != FP32_ONE);
    __shared__ float tt[32][33];
    int layer = blockIdx.z;
    size_t inoff = (size_t)layer * perlin;
    ushort_t* out = wbuf + (size_t)layer * WL + outoff;
    int tx = threadIdx.x & 31, ty = threadIdx.x >> 5;
    int n0 = blockIdx.x * 32, k0 = blockIdx.y * 32;
#pragma unroll
    for (int it = 0; it < 4; ++it)
        tt[ty + it * 8][tx] = ldx(in, inoff + (size_t)(k0 + ty + it * 8) * N + n0 + tx, isbf);
    __syncthreads();
#pragma unroll
    for (int it = 0; it < 4; ++it)
        out[(size_t)(n0 + ty + it * 8) * K + k0 + tx] = f2b(tt[tx][ty + it * 8]);
}

__global__ __launch_bounds__(256) void cvtL(const void* __restrict__ in, size_t perlin,
                                            ushort_t* __restrict__ wbuf, size_t outoff,
                                            const unsigned int* __restrict__ dtp, int nelem) {
    const bool isbf = (dtp[0] != FP32_ONE);
    int layer = blockIdx.z;
    int i = blockIdx.x * 256 + threadIdx.x;
    if (i < nelem)
        wbuf[(size_t)layer * WL + outoff + i] = f2b(ldx(in, (size_t)layer * perlin + i, isbf));
}

// C[M,N] = A[M,K](bf16, lda) x B^T[n][k](bf16, ldb).
// EPI: 0 none, 1 +bias, 2 +bias+exact GELU. Swapped-operand MFMA: lane owns
// C[row l16][4 consecutive cols] -> 8B packed bf16 stores.
// r16: 512 threads / 8 waves (2 x 4), wave tile 64x32, acc[4][2] (32 AGPR)
// -> low register footprint -> up to 32 waves/CU. Double-buffered 32KB LDS,
// counted vmcnt(2) (2 loads/thread/tile), stage t+2 into freed buffer.
template<int EPI>
__global__ __launch_bounds__(512)
void mfma_gemm(const ushort_t* __restrict__ A, int lda,
               const ushort_t* __restrict__ Bt, int ldb,
               const void* __restrict__ biasv, size_t biasoff,
               ushort_t* __restrict__ C, int ldc,
               size_t bzoff, size_t czoff,
               const unsigned int* __restrict__ dtp, int M, int N, int K) {
    const bool isbf = (dtp[0] != FP32_ONE);
    __shared__ ushort_t As[2][128 * 32];
    __shared__ ushort_t Bs[2][128 * 32];
    const int tid = threadIdx.x;
    Bt += (size_t)blockIdx.z * bzoff;
    C  += (size_t)blockIdx.z * czoff;
    // XCD swizzle (nwg % 8 == 0 at all call sites): contiguous swz chunk per
    // XCD; within the chunk bn varies fastest (B panel L2-resident).
    const int nwg = gridDim.x * gridDim.y;
    const int wg  = blockIdx.y * gridDim.x + blockIdx.x;
    const int cpx = nwg >> 3;
    const int swz = (wg & 7) * cpx + (wg >> 3);
    const int bm = (swz / gridDim.y) * 128;
    const int bn = (swz % gridDim.y) * 128;
    const int w = tid >> 6, lane = tid & 63;
    const int wr = w >> 2, wc = w & 3;           // 2 x 4 wave grid
    const int quad = lane >> 4, l16 = lane & 15;
    const int fsw  = (l16 >> 1) & 3;

    // staging: thread covers row tid>>2 (0..127), chunk tid&3, both operands.
    // LDS phys chunk c of row r holds global chunk c ^ ((r>>1)&3).
    const int srow = tid >> 2;
    const int ssw  = (srow >> 1) & 3;
    const int sck  = (tid & 3) ^ ssw;
    const ushort_t* gA = A  + (size_t)(bm + srow) * lda + sck * 8;
    const ushort_t* gB = Bt + (size_t)(bn + srow) * ldb + sck * 8;
    const int ldst = tid * 8;

#define STAGE_T(kt, bi) do {                                  \
        int _k0 = (kt) << 5;                                  \
        async16(gA + _k0, As[bi] + ldst);                     \
        async16(gB + _k0, Bs[bi] + ldst);                     \
    } while (0)

    f32x4 acc[4][2];
#pragma unroll
    for (int i = 0; i < 4; ++i)
#pragma unroll
        for (int j = 0; j < 2; ++j)
#pragma unroll
            for (int r = 0; r < 4; ++r) acc[i][j][r] = 0.f;

    const int nt = K >> 5;      // >= 16 at all call sites
    STAGE_T(0, 0);
    STAGE_T(1, 1);
    for (int t = 0; t < nt; ++t) {
        const int cur = t & 1;
        // tile t forced complete; tile t+1 (2 loads/thread) stays in flight.
        if (t + 1 < nt) asm volatile("s_waitcnt vmcnt(2)" ::: "memory");
        else            asm volatile("s_waitcnt vmcnt(0)" ::: "memory");
        __builtin_amdgcn_s_barrier();
        asm volatile("" ::: "memory");   // keep LDS reads below the barrier

        short8 af[4], bf[2];
#pragma unroll
        for (int tt = 0; tt < 4; ++tt) {
            int ra = wr * 64 + tt * 16 + l16;
            af[tt] = *(const short8*)(As[cur] + ra * 32 + ((quad ^ fsw) * 8));
        }
#pragma unroll
        for (int tc = 0; tc < 2; ++tc) {
            int rb = wc * 32 + tc * 16 + l16;
            bf[tc] = *(const short8*)(Bs[cur] + rb * 32 + ((quad ^ fsw) * 8));
        }
#pragma unroll
        for (int tr = 0; tr < 4; ++tr)
#pragma unroll
            for (int tc = 0; tc < 2; ++tc)
                acc[tr][tc] = __builtin_amdgcn_mfma_f32_16x16x32_bf16(bf[tc], af[tr], acc[tr][tc], 0, 0, 0);

        asm volatile("s_waitcnt lgkmcnt(0)" ::: "memory");  // reads done before overwrite
        __builtin_amdgcn_s_barrier();
        if (t + 2 < nt) STAGE_T(t + 2, cur);   // refill the buffer just freed
    }
#undef STAGE_T

    float bv[2][4];
    if (EPI >= 1) {
#pragma unroll
        for (int tc = 0; tc < 2; ++tc)
#pragma unroll
            for (int r = 0; r < 4; ++r)
                bv[tc][r] = ldx(biasv, biasoff + bn + wc * 32 + tc * 16 + quad * 4 + r, isbf);
    }
#pragma unroll
    for (int tr = 0; tr < 4; ++tr) {
        int grow = bm + wr * 64 + tr * 16 + l16;
#pragma unroll
        for (int tc = 0; tc < 2; ++tc) {
            int gcb = bn + wc * 32 + tc * 16 + quad * 4;
            float x[4];
#pragma unroll
            for (int r = 0; r < 4; ++r) {
                float v = acc[tr][tc][r];
                if (EPI >= 1) v += bv[tc][r];
                if (EPI == 2) v = fast_gelu(v);
                x[r] = v;
            }
            uint2 pk;
            pk.x = (unsigned)f2b(x[0]) | ((unsigned)f2b(x[1]) << 16);
            pk.y = (unsigned)f2b(x[2]) | ((unsigned)f2b(x[3]) << 16);
            *(uint2*)(C + (size_t)grow * ldc + gcb) = pk;
        }
    }
}

// MFMA banded attention; PV uses swapped operands (packed 8B output stores).
// LDS XOR chunk-swizzle (r10): Ks/Rs chunk q of row r at (q ^ (r&7));
// VT/Ps chunk q of row r at (q ^ (r&15)). Same on write and read.
// XCD-aware block remap (r14): each XCD owns 4 batches, i0 fastest.
__global__ __launch_bounds__(256) void attn_mfma(
    ushort_t* __restrict__ qkv, const ushort_t* __restrict__ krb,
    const void* __restrict__ rwb, const void* __restrict__ rrb, size_t boff,
    const void* __restrict__ im,
    const unsigned int* __restrict__ dtp) {
    const bool isbf = (dtp[0] != FP32_ONE);
    __shared__ ushort_t Ks[128 * 64];
    __shared__ ushort_t VT[64 * 128];
    __shared__ ushort_t Rs[64 * 64];
    __shared__ float    BD2[4 * 16 * 64];
    __shared__ ushort_t Ps[4 * 16 * 128];
    __shared__ float    imk[128];
    __shared__ float    imq[64];

    const int tid = threadIdx.x;
    const int bid  = (blockIdx.z * gridDim.y + blockIdx.y) * gridDim.x + blockIdx.x;
    const int xcd  = bid & 7, slot = bid >> 3;
    const int i0 = (slot & 7) * 64;
    const int n  = (slot >> 3) & 7;
    const int b  = xcd * 4 + (slot >> 6);
    const int o  = OMEGA_C[n];
    const int noff = n * DH;
    const int j0 = i0 - 64;
    const int w = tid >> 6, lane = tid & 63;
    const int quad = lane >> 4, l16 = lane & 15;

#pragma unroll
    for (int it = 0; it < 4; ++it) {
        int q4 = it * 256 + tid;
        int c  = q4 >> 3, ch = q4 & 7;
        int jc = j0 + c; jc = jc < 0 ? 0 : jc;
        size_t rowb = (size_t)(jc * B_ + b) * QKV_LD + noff;
        *(uint4*)(Ks + c * 64 + ((ch ^ (c & 7)) << 3)) = *(const uint4*)(qkv + rowb + 512 + ch * 8);
        ushort_t v8[8];
        *(uint4*)v8 = *(const uint4*)(qkv + rowb + 1024 + ch * 8);
#pragma unroll
        for (int e = 0; e < 8; ++e) {
            int vr = ch * 8 + e;
            VT[vr * 128 + (((c >> 3) ^ (vr & 15)) << 3) + (c & 7)] = v8[e];
        }
    }
#pragma unroll
    for (int it = 0; it < 2; ++it) {
        int q4 = it * 256 + tid;
        int m = q4 >> 3, ch = q4 & 7;
        *(uint4*)(Rs + m * 64 + ((ch ^ (m & 7)) << 3)) =
            *(const uint4*)(krb + (size_t)(512 - m) * 512 + noff + ch * 8);
    }
    if (tid < 128) {
        int j = j0 + tid;
        imk[tid] = (j >= 0) ? ldx(im, b * S_ + j, isbf) : 0.f;
    } else if (tid < 192) {
        imq[tid - 128] = ldx(im, b * S_ + i0 + (tid - 128), isbf);
    }
    __syncthreads();

    const int qrow = i0 + w * 16 + l16;
    size_t qbase = (size_t)(qrow * B_ + b) * QKV_LD + noff;
    short8 aw[2], ar[2];
#pragma unroll
    for (int kc = 0; kc < 2; ++kc) {
        int kof = kc * 32 + quad * 8;
        ushort_t qe[8];
        *(uint4*)qe = *(const uint4*)(qkv + qbase + kof);
#pragma unroll
        for (int e = 0; e < 8; ++e) {
            float f = b2f(qe[e]);
            ((ushort_t*)&aw[kc])[e] = f2b(f + ldx(rwb, boff + noff + kof + e, isbf));
            ((ushort_t*)&ar[kc])[e] = f2b(f + ldx(rrb, boff + noff + kof + e, isbf));
        }
    }

    f32x4 accs[8];
#pragma unroll
    for (int ct = 0; ct < 8; ++ct) {
        int kr = ct * 16 + l16;
        short8 b0 = *(const short8*)(Ks + kr * 64 + ((quad ^ (kr & 7)) << 3));
        short8 b1 = *(const short8*)(Ks + kr * 64 + (((quad + 4) ^ (kr & 7)) << 3));
        f32x4 z = {0.f, 0.f, 0.f, 0.f};
        z = __builtin_amdgcn_mfma_f32_16x16x32_bf16(aw[0], b0, z, 0, 0, 0);
        z = __builtin_amdgcn_mfma_f32_16x16x32_bf16(aw[1], b1, z, 0, 0, 0);
        accs[ct] = z;
    }
    float* BD2w = BD2 + w * 16 * 64;
#pragma unroll
    for (int mt = 0; mt < 4; ++mt) {
        int rr = mt * 16 + l16;
        short8 b0 = *(const short8*)(Rs + rr * 64 + ((quad ^ (rr & 7)) << 3));
        short8 b1 = *(const short8*)(Rs + rr * 64 + (((quad + 4) ^ (rr & 7)) << 3));
        f32x4 z = {0.f, 0.f, 0.f, 0.f};
        z = __builtin_amdgcn_mfma_f32_16x16x32_bf16(ar[0], b0, z, 0, 0, 0);
        z = __builtin_amdgcn_mfma_f32_16x16x32_bf16(ar[1], b1, z, 0, 0, 0);
#pragma unroll
        for (int r = 0; r < 4; ++r)
            BD2w[(quad * 4 + r) * 64 + mt * 16 + l16] = z[r];
    }

    float im_i[4];
#pragma unroll
    for (int r = 0; r < 4; ++r) im_i[r] = imq[w * 16 + quad * 4 + r];

    float sc[8][4];
#pragma unroll
    for (int ct = 0; ct < 8; ++ct) {
        int cl = ct * 16 + l16;
        float imk_c = imk[cl];
#pragma unroll
        for (int r = 0; r < 4; ++r) {
            int qrl = w * 16 + quad * 4 + r;
            int rel = qrl + 64 - cl;
            int relc = rel < 0 ? 0 : (rel > 63 ? 63 : rel);
            float bd = BD2w[(quad * 4 + r) * 64 + relc];
            bool valid = (rel >= 0) && (rel < o) && (rel <= i0 + qrl)
                         && (im_i[r] + imk_c <= 0.f);
            sc[ct][r] = valid ? (accs[ct][r] + bd) * 0.125f : -1e30f;
        }
    }
    float rl[4];
#pragma unroll
    for (int r = 0; r < 4; ++r) {
        float mx = sc[0][r];
#pragma unroll
        for (int ct = 1; ct < 8; ++ct) mx = fmaxf(mx, sc[ct][r]);
        mx = row16_max(mx);
        float l = 0.f;
#pragma unroll
        for (int ct = 0; ct < 8; ++ct) {
            float pv = __expf(sc[ct][r] - mx);
            sc[ct][r] = pv;
            l += pv;
        }
        l = row16_sum(l);
        rl[r] = 1.f / l;
    }
    ushort_t* Pw = Ps + w * 16 * 128;
#pragma unroll
    for (int ct = 0; ct < 8; ++ct)
#pragma unroll
        for (int r = 0; r < 4; ++r) {
            int prow = quad * 4 + r;
            Pw[prow * 128 + ((((ct * 2 + (l16 >> 3)) ^ prow) & 15) << 3) + (l16 & 7)]
                = f2b(sc[ct][r] * rl[r]);
        }

    short8 aP[4];
#pragma unroll
    for (int kc = 0; kc < 4; ++kc)
        aP[kc] = *(const short8*)(Pw + l16 * 128 + ((((kc * 4 + quad) ^ l16) & 15) << 3));

    const int qg = i0 + w * 16 + l16;
    const size_t obase = (size_t)(qg * B_ + b) * QKV_LD + noff;
#pragma unroll
    for (int dt = 0; dt < 4; ++dt) {
        f32x4 accT = {0.f, 0.f, 0.f, 0.f};
#pragma unroll
        for (int kc = 0; kc < 4; ++kc) {
            int vrow = dt * 16 + l16;
            short8 bV = *(const short8*)(VT + vrow * 128 + ((((kc * 4 + quad) ^ (vrow & 15)) & 15) << 3));
            accT = __builtin_amdgcn_mfma_f32_16x16x32_bf16(bV, aP[kc], accT, 0, 0, 0);
        }
        uint2 pk;
        pk.x = (unsigned)f2b(accT[0]) | ((unsigned)f2b(accT[1]) << 16);
        pk.y = (unsigned)f2b(accT[2]) | ((unsigned)f2b(accT[3]) << 16);
        *(uint2*)(qkv + obase + dt * 16 + quad * 4) = pk;
    }
}

// h = LayerNorm(x + h)*w + b. Wave-per-row, uint4, no barriers.
__global__ __launch_bounds__(256) void add_ln_kernel(
    const ushort_t* __restrict__ x, ushort_t* __restrict__ h,
    const void* __restrict__ w, const void* __restrict__ b, size_t boff,
    const unsigned int* __restrict__ dtp) {
    const bool isbf = (dtp[0] != FP32_ONE);
    int lane = threadIdx.x & 63;
    int row = blockIdx.x * 4 + (threadIdx.x >> 6);
    size_t base = (size_t)row * D_ + lane * 8;
    ushort_t xe[8], he[8];
    *(uint4*)xe = *(const uint4*)(x + base);
    *(uint4*)he = *(const uint4*)(h + base);
    float v[8];
    float s = 0.f, ss = 0.f;
#pragma unroll
    for (int e = 0; e < 8; ++e) {
        v[e] = b2f(xe[e]) + b2f(he[e]);
        s += v[e]; ss += v[e] * v[e];
    }
    dpp_sum64(s); dpp_sum64(ss);
    float S = rlane(s, 63), SS = rlane(ss, 63);
    float mu  = S * (1.f / D_);
    float var = fmaxf(SS * (1.f / D_) - mu * mu, 0.f);
    float inv = rsqrtf(var + 1e-8f);
    ushort_t oe[8];
#pragma unroll
    for (int e = 0; e < 8; ++e)
        oe[e] = f2b((v[e] - mu) * inv * ldx(w, boff + lane * 8 + e, isbf)
                    + ldx(b, boff + lane * 8 + e, isbf));
    *(uint4*)(h + base) = *(uint4*)oe;
}

__global__ __launch_bounds__(256) void writeout_kernel(const ushort_t* __restrict__ h,
                                                       void* __restrict__ out,
                                                       const unsigned int* __restrict__ dtp) {
    const bool isbf = (dtp[0] != FP32_ONE);
    int idx = blockIdx.x * 256 + threadIdx.x;        // over M_*D_/8
    int d8 = idx & 63;
    int rest = idx >> 6;                             // b*S + s
    int s = rest & (S_ - 1), b = rest >> 9;
    ushort_t ve[8];
    *(uint4*)ve = *(const uint4*)(h + ((size_t)(s * B_ + b) << 9) + d8 * 8);
    if (isbf) {
        *(uint4*)((ushort_t*)out + (size_t)idx * 8) = *(uint4*)ve;
    } else {
        float* op = (float*)out + (size_t)idx * 8;
        ((float4*)op)[0] = make_float4(b2f(ve[0]), b2f(ve[1]), b2f(ve[2]), b2f(ve[3]));
        ((float4*)op)[1] = make_float4(b2f(ve[4]), b2f(ve[5]), b2f(ve[6]), b2f(ve[7]));
    }
}

extern "C" void kernel_launch(void* const* d_in, const int* in_sizes, int n_in,
                              void* d_out, int out_size, void* d_ws, size_t ws_size,
                              hipStream_t stream) {
    (void)in_sizes; (void)n_in; (void)out_size; (void)ws_size;
    const int*  ids = (const int*)d_in[0];
    const void* im  = d_in[1];
    const void* emb = d_in[2];
    const void* Wq = d_in[3], *Wk = d_in[4], *Wv = d_in[5], *Wr = d_in[6], *Wo = d_in[7];
    const void* rrb = d_in[8], *rwb = d_in[9];
    const void* lnaw = d_in[10], *lnab = d_in[11];
    const void* W1 = d_in[12], *b1 = d_in[13], *W2 = d_in[14], *b2 = d_in[15];
    const void* lnfw = d_in[16], *lnfb = d_in[17];
    const unsigned int* dtp = (const unsigned int*)d_in[10];  // dtype probe

    // ---- workspace layout, ~160 MB ----
    char* wsb = (char*)d_ws;
    ushort_t* h    = (ushort_t*)wsb;                   // [0,16)    bf16 16384x512
    ushort_t* qkv  = (ushort_t*)(wsb + (16u << 20));   // [16,64)   bf16 16384x1536
    ushort_t* tmp  = (ushort_t*)(wsb + (64u << 20));   // [64,80)   bf16 16384x512
    ushort_t* ff1  = (ushort_t*)(wsb + (80u << 20));   // [80,144)  bf16 16384x2048
    ushort_t* wbuf = (ushort_t*)(wsb + (144u << 20));  // [144,157) weights
    ushort_t* posb = (ushort_t*)(wsb + (157u << 20));  // [157,158) bf16 1024x512
    ushort_t* krb0 = (ushort_t*)(wsb + (158u << 20));  // [158,159) bf16 1024x512
    ushort_t* krb1 = (ushort_t*)(wsb + (159u << 20));  // [159,160)

    embed_kernel<<<4096, 256, 0, stream>>>(ids, emb, h, dtp);
    posemb_kernel<<<1024, 256, 0, stream>>>(posb);

    transp_cvt4<<<dim3(16, 16, 8), 256, 0, stream>>>(Wq, Wk, Wv, Wr, wbuf, dtp);
    cvtL<<<dim3(1024, 1, 2), 256, 0, stream>>>(Wo, 262144, wbuf, 1048576, dtp, 262144);
    transp_cvtL<<<dim3(64, 16, 2), 256, 0, stream>>>(W1, 1048576, wbuf, 1310720, dtp, 512, 2048);
    transp_cvtL<<<dim3(16, 64, 2), 256, 0, stream>>>(W2, 1048576, wbuf, 2359296, dtp, 2048, 512);

    // k_r for BOTH layers in one dispatch (z = layer; B stride WL, C stride 512KB)
    mfma_gemm<0><<<dim3(8, 4, 2), 512, 0, stream>>>(posb, 512, wbuf + 786432, 512, nullptr, 0,
                                                    krb0, 512, WL, 524288, dtp, 1024, 512, 512);

    for (int l = 0; l < 2; ++l) {
        size_t boff = (size_t)l * 512;
        size_t b1off = (size_t)l * 2048;
        ushort_t* qkvT = wbuf + (size_t)l * WL;
        ushort_t* woc  = qkvT + 1048576;
        ushort_t* w1T  = woc  + 262144;
        ushort_t* w2T  = w1T  + 1048576;
        ushort_t* krb  = l ? krb1 : krb0;

        // fused q|k|v = h @ [Wq|Wk|Wv] (16384x1536)
        mfma_gemm<0><<<dim3(128, 12), 512, 0, stream>>>(h, 512, qkvT, 512, nullptr, 0, qkv, QKV_LD, 0, 0, dtp, M_, QKV_LD, 512);

        attn_mfma<<<dim3(8, 32, 8), 256, 0, stream>>>(qkv, krb, rwb, rrb, boff, im, dtp);

        // attn_out = av @ Wo^T (av in q slots, lda=1536)
        mfma_gemm<0><<<dim3(128, 4), 512, 0, stream>>>(qkv, QKV_LD, woc, 512, nullptr, 0, tmp, 512, 0, 0, dtp, M_, 512, 512);
        add_ln_kernel<<<4096, 256, 0, stream>>>(tmp, h, lnaw, lnab, boff, dtp);

        // FFN: single FF1 (N=2048) and single FF2 (K=2048)
        mfma_gemm<2><<<dim3(128, 16), 512, 0, stream>>>(h, 512, w1T, 512, b1, b1off, ff1, DI, 0, 0, dtp, M_, DI, 512);
        mfma_gemm<1><<<dim3(128, 4),  512, 0, stream>>>(ff1, DI, w2T, 2048, b2, boff, tmp, 512, 0, 0, dtp, M_, 512, DI);
        add_ln_kernel<<<4096, 256, 0, stream>>>(tmp, h, lnfw, lnfb, boff, dtp);
    }

    writeout_kernel<<<4096, 256, 0, stream>>>(h, d_out, dtp);
}